// Round 2
// baseline (751.193 us; speedup 1.0000x reference)
//
#include <hip/hip_runtime.h>
#include <cstdint>
#include <cstddef>

#define NN 8192
#define EE 262144
#define ET 270336   // EE + NN self loops

using short8  = __attribute__((ext_vector_type(8))) short;
using floatx4 = __attribute__((ext_vector_type(4))) float;

__device__ __forceinline__ unsigned short f2bf(float f) {
  unsigned int u = __float_as_uint(f);
  u += 0x7fffu + ((u >> 16) & 1u);          // RNE
  return (unsigned short)(u >> 16);
}

// ---------------- CSR build, both graphs in one launch ----------------
__global__ void edge_hist2_k(const int* __restrict__ ei_t, const int* __restrict__ ei_e,
                             int* __restrict__ cnt_t, int* __restrict__ cnt_e) {
  int idx = blockIdx.x * 256 + threadIdx.x;
  int g = idx >= ET;                        // block-uniform (ET % 256 == 0)
  int e = g ? idx - ET : idx;
  const int* ei = g ? ei_e : ei_t;
  int* cnt = g ? cnt_e : cnt_t;
  int d = (e < EE) ? ei[EE + e] : (e - EE);
  atomicAdd(&cnt[d], 1);
}

__global__ void scan2_k(int* cnt_t, int* off_t, int* cnt_e, int* off_e) {
  int* cnt = blockIdx.x ? cnt_e : cnt_t;    // pos aliases cnt (overwritten)
  int* off = blockIdx.x ? off_e : off_t;
  __shared__ int s[1024];
  int t = threadIdx.x;
  int v[8]; int base = t * 8; int sum = 0;
  #pragma unroll
  for (int j = 0; j < 8; ++j) { v[j] = cnt[base + j]; sum += v[j]; }
  s[t] = sum; __syncthreads();
  for (int o = 1; o < 1024; o <<= 1) {
    int x = (t >= o) ? s[t - o] : 0;
    __syncthreads();
    s[t] += x;
    __syncthreads();
  }
  int excl = s[t] - sum;
  #pragma unroll
  for (int j = 0; j < 8; ++j) { off[base + j] = excl; cnt[base + j] = excl; excl += v[j]; }
  if (t == 1023) off[NN] = excl;
}

__global__ void edge_scatter2_k(const int* __restrict__ ei_t, const int* __restrict__ ei_e,
                                int* __restrict__ pos_t, int* __restrict__ pos_e,
                                int* __restrict__ srcs_t, int* __restrict__ srcs_e) {
  int idx = blockIdx.x * 256 + threadIdx.x;
  int g = idx >= ET;
  int e = g ? idx - ET : idx;
  const int* ei = g ? ei_e : ei_t;
  int* pos = g ? pos_e : pos_t;
  int* srcs = g ? srcs_e : srcs_t;
  int sv, d;
  if (e < EE) { sv = ei[e]; d = ei[EE + e]; } else { sv = d = e - EE; }
  int p = atomicAdd(&pos[d], 1);
  srcs[p] = sv;
}

// ---------------- shared GEMM inner loop ----------------
__device__ __forceinline__ void gemm_core(const float* __restrict__ A, int lda, int K,
                                          const float* __restrict__ Bs, int row0, int col,
                                          float acc[8]) {
  #pragma unroll
  for (int r = 0; r < 8; ++r) acc[r] = 0.f;
  for (int k = 0; k < K; k += 4) {
    float b0 = Bs[(k + 0) * 32 + col], b1 = Bs[(k + 1) * 32 + col];
    float b2 = Bs[(k + 2) * 32 + col], b3 = Bs[(k + 3) * 32 + col];
    #pragma unroll
    for (int r = 0; r < 8; ++r) {
      const float4 a4 = *(const float4*)(A + (size_t)(row0 + r) * lda + k);
      acc[r] = fmaf(a4.x, b0, acc[r]);
      acc[r] = fmaf(a4.y, b1, acc[r]);
      acc[r] = fmaf(a4.z, b2, acc[r]);
      acc[r] = fmaf(a4.w, b3, acc[r]);
    }
  }
}

// ---------------- mm_x: h1 = x@gat1_W (+att_sd epilogue), hg1 = x@gcn1_W ----------------
__global__ __launch_bounds__(256) void mm_x_k(const float* __restrict__ x,
    const float* __restrict__ Wgat, const float* __restrict__ Wgcn,
    const float* __restrict__ as_w, const float* __restrict__ ad_w,
    float* __restrict__ h1, float* __restrict__ hg1,
    float* __restrict__ a_s1, float* __restrict__ a_d1) {
  __shared__ float Bs[256 * 32];
  const int tid = threadIdx.x, by = blockIdx.y;
  const bool gat = by < 4;
  const int NC = gat ? 128 : 64;
  const int c0 = gat ? by * 32 : (by - 4) * 32;
  const float* B = gat ? Wgat : Wgcn;
  for (int idx = tid; idx < 256 * 32; idx += 256)
    Bs[idx] = B[(idx >> 5) * NC + c0 + (idx & 31)];
  __syncthreads();
  const int row0 = blockIdx.x * 64 + (tid >> 5) * 8;
  const int col = tid & 31;
  float acc[8];
  gemm_core(x, 256, 256, Bs, row0, col, acc);
  if (gat) {
    #pragma unroll
    for (int r = 0; r < 8; ++r) h1[(size_t)(row0 + r) * 128 + c0 + col] = acc[r];
    const int head = c0 >> 6;
    const float asw = as_w[head * 64 + (c0 & 63) + col];
    const float adw = ad_w[head * 64 + (c0 & 63) + col];
    float ps[8], pd[8];
    #pragma unroll
    for (int r = 0; r < 8; ++r) { ps[r] = acc[r] * asw; pd[r] = acc[r] * adw; }
    #pragma unroll
    for (int m = 16; m >= 1; m >>= 1)
      #pragma unroll
      for (int r = 0; r < 8; ++r) { ps[r] += __shfl_xor(ps[r], m); pd[r] += __shfl_xor(pd[r], m); }
    if (col == 0) {
      #pragma unroll
      for (int r = 0; r < 8; ++r) {
        atomicAdd(&a_s1[(row0 + r) * 2 + head], ps[r]);
        atomicAdd(&a_d1[(row0 + r) * 2 + head], pd[r]);
      }
    }
  } else {
    #pragma unroll
    for (int r = 0; r < 8; ++r) hg1[(size_t)(row0 + r) * 64 + c0 + col] = acc[r];
  }
}

// ---------------- GAT aggregation ----------------
template<int H, int C>
__device__ __forceinline__ void gat_agg_body(const float* __restrict__ h,
    const float* __restrict__ a_s, const float* __restrict__ a_d,
    const int* __restrict__ off, const int* __restrict__ srcs,
    const float* __restrict__ bias, float* __restrict__ out, int ldout, int b) {
  constexpr int HC = H * C;
  const int tid = threadIdx.x;
  const int hd = tid / C;
  const int r0 = off[b], r1 = off[b + 1];
  __shared__ int s_src[HC];
  __shared__ float s_w[HC][H];
  float ad[H];
  #pragma unroll
  for (int hh = 0; hh < H; ++hh) ad[hh] = a_d[b * H + hh];
  float acc = 0.f, den = 0.f;
  for (int base = r0; base < r1; base += HC) {
    __syncthreads();
    int e = base + tid;
    if (e < r1) {
      int sv = srcs[e];
      s_src[tid] = sv;
      #pragma unroll
      for (int hh = 0; hh < H; ++hh) {
        float xv = a_s[sv * H + hh] + ad[hh];
        xv = xv > 0.f ? xv : 0.2f * xv;     // leaky_relu 0.2
        s_w[tid][hh] = __expf(xv);
      }
    }
    __syncthreads();
    int cnt = min(HC, r1 - base);
    for (int j = 0; j < cnt; ++j) {
      float wv = s_w[j][hd];
      den += wv;
      acc = fmaf(wv, h[(size_t)s_src[j] * HC + tid], acc);
    }
  }
  float o = acc / den + bias[tid];
  out[(size_t)b * ldout + tid] = o > 0.f ? o : (__expf(o) - 1.f);  // elu
}

template<int H, int C>
__global__ void gat_agg_k(const float* __restrict__ h, const float* __restrict__ a_s,
                          const float* __restrict__ a_d, const int* __restrict__ off,
                          const int* __restrict__ srcs, const float* __restrict__ bias,
                          float* __restrict__ out, int ldout) {
  gat_agg_body<H, C>(h, a_s, a_d, off, srcs, bias, out, ldout, blockIdx.x);
}

// ---------------- merged: gat1 aggregation (blocks 0..NN) + gcn1 agg+gemv (2 nodes/blk) ----
__global__ __launch_bounds__(128) void agg1_k(
    const float* __restrict__ h1, const float* __restrict__ a_s1, const float* __restrict__ a_d1,
    const int* __restrict__ off_t, const int* __restrict__ src_t,
    const float* __restrict__ gat1_b, float* __restrict__ g1out,
    const float* __restrict__ hg1, const int* __restrict__ off_e, const int* __restrict__ src_e,
    const float* __restrict__ gcn1_b, const float* __restrict__ gcn2_W, float* __restrict__ h2g) {
  const int tid = threadIdx.x;
  if (blockIdx.x < NN) {
    gat_agg_body<2, 64>(h1, a_s1, a_d1, off_t, src_t, gat1_b, g1out, 128, blockIdx.x);
  } else {
    const int nb = (blockIdx.x - NN) * 2;
    const int sub = tid >> 6, t = tid & 63;
    const int node = nb + sub;
    __shared__ int s_src2[2][64];
    __shared__ float s_nrm2[2][64];
    __shared__ float s_row2[2][64];
    const int r0 = off_e[node], r1 = off_e[node + 1];
    const int cA = off_e[nb + 1] - off_e[nb];
    const int cB = off_e[nb + 2] - off_e[nb + 1];
    const int trips = (max(cA, cB) + 63) >> 6;
    float dinv_b = rsqrtf((float)max(r1 - r0, 1));
    float acc = 0.f;
    for (int it = 0; it < trips; ++it) {
      __syncthreads();
      int e = r0 + it * 64 + t;
      if (e < r1) {
        int sv = src_e[e];
        s_src2[sub][t] = sv;
        int ds = off_e[sv + 1] - off_e[sv];
        s_nrm2[sub][t] = dinv_b * rsqrtf((float)max(ds, 1));
      }
      __syncthreads();
      int cnt = min(64, r1 - (r0 + it * 64));
      for (int j = 0; j < cnt; ++j)
        acc = fmaf(s_nrm2[sub][j], hg1[(size_t)s_src2[sub][j] * 64 + t], acc);
    }
    s_row2[sub][t] = fmaxf(acc + gcn1_b[t], 0.f);
    __syncthreads();
    float acc2 = 0.f;
    for (int k = 0; k < 64; ++k)
      acc2 = fmaf(s_row2[sub][k], gcn2_W[k * 64 + t], acc2);
    h2g[(size_t)node * 64 + t] = acc2;
  }
}

// ---------------- merged: mm_gat2 (blocks 0..256) + gcn_agg2 (4 nodes/blk) ----------------
__global__ __launch_bounds__(256) void mm2_k(
    const float* __restrict__ g1out, const float* __restrict__ gat2_W,
    const float* __restrict__ gat2_as, const float* __restrict__ gat2_ad,
    float* __restrict__ h2, float* __restrict__ a_s2, float* __restrict__ a_d2,
    const float* __restrict__ h2g, const int* __restrict__ off_e, const int* __restrict__ src_e,
    const float* __restrict__ gcn2_b, float* __restrict__ hekg) {
  const int tid = threadIdx.x;
  if (blockIdx.x < 256) {
    __shared__ float Bs[128 * 32];
    const int bx = blockIdx.x & 127;
    const int c0 = (blockIdx.x >> 7) * 32;
    for (int idx = tid; idx < 128 * 32; idx += 256)
      Bs[idx] = gat2_W[(idx >> 5) * 64 + c0 + (idx & 31)];
    __syncthreads();
    const int row0 = bx * 64 + (tid >> 5) * 8;
    const int col = tid & 31;
    float acc[8];
    gemm_core(g1out, 128, 128, Bs, row0, col, acc);
    const float asw = gat2_as[c0 + col];
    const float adw = gat2_ad[c0 + col];
    float ps[8], pd[8];
    #pragma unroll
    for (int r = 0; r < 8; ++r) {
      h2[(size_t)(row0 + r) * 64 + c0 + col] = acc[r];
      ps[r] = acc[r] * asw; pd[r] = acc[r] * adw;
    }
    #pragma unroll
    for (int m = 16; m >= 1; m >>= 1)
      #pragma unroll
      for (int r = 0; r < 8; ++r) { ps[r] += __shfl_xor(ps[r], m); pd[r] += __shfl_xor(pd[r], m); }
    if (col == 0) {
      #pragma unroll
      for (int r = 0; r < 8; ++r) {
        atomicAdd(&a_s2[row0 + r], ps[r]);
        atomicAdd(&a_d2[row0 + r], pd[r]);
      }
    }
  } else {
    const int nb = (blockIdx.x - 256) * 4;
    const int sub = tid >> 6, t = tid & 63;
    const int node = nb + sub;
    __shared__ int s_src4[4][64];
    __shared__ float s_nrm4[4][64];
    const int r0 = off_e[node], r1 = off_e[node + 1];
    int cmax = 0;
    #pragma unroll
    for (int i = 0; i < 4; ++i) cmax = max(cmax, off_e[nb + i + 1] - off_e[nb + i]);
    const int trips = (cmax + 63) >> 6;
    float dinv_b = rsqrtf((float)max(r1 - r0, 1));
    float acc = 0.f;
    for (int it = 0; it < trips; ++it) {
      __syncthreads();
      int e = r0 + it * 64 + t;
      if (e < r1) {
        int sv = src_e[e];
        s_src4[sub][t] = sv;
        int ds = off_e[sv + 1] - off_e[sv];
        s_nrm4[sub][t] = dinv_b * rsqrtf((float)max(ds, 1));
      }
      __syncthreads();
      int cnt = min(64, r1 - (r0 + it * 64));
      for (int j = 0; j < cnt; ++j)
        acc = fmaf(s_nrm4[sub][j], h2g[(size_t)s_src4[sub][j] * 64 + t], acc);
    }
    hekg[(size_t)node * 64 + t] = fmaxf(acc + gcn2_b[t], 0.f);
  }
}

// ---------------- qkv projections (+V transpose) ----------------
__global__ __launch_bounds__(256) void mm_qkv_k(const float* __restrict__ htkg,
    const float* __restrict__ hekg,
    const float* __restrict__ Wq, const float* __restrict__ bq,
    const float* __restrict__ Wk, const float* __restrict__ bk,
    const float* __restrict__ Wv, const float* __restrict__ bv,
    unsigned short* __restrict__ qb, unsigned short* __restrict__ kb,
    unsigned short* __restrict__ Vt) {
  __shared__ float Bs[64 * 32];
  __shared__ float Ts[32][65];
  const int tid = threadIdx.x, by = blockIdx.y;
  const int kind = by >> 1;
  const int c0 = (by & 1) * 32;
  const float* A = (kind == 0) ? htkg : hekg;
  const float* B = (kind == 0) ? Wq : (kind == 1) ? Wk : Wv;
  const float* bias = (kind == 0) ? bq : (kind == 1) ? bk : bv;
  for (int idx = tid; idx < 64 * 32; idx += 256)
    Bs[idx] = B[(idx >> 5) * 64 + c0 + (idx & 31)];
  __syncthreads();
  const int row0 = blockIdx.x * 64 + (tid >> 5) * 8;
  const int col = tid & 31;
  float acc[8];
  gemm_core(A, 64, 64, Bs, row0, col, acc);
  const float bb = bias[c0 + col];
  if (kind == 0) {
    const float SCL = 0.17677669529663687f * 1.4426950408889634f;  // 1/sqrt(32) * log2(e)
    #pragma unroll
    for (int r = 0; r < 8; ++r)
      qb[(size_t)(row0 + r) * 64 + c0 + col] = f2bf((acc[r] + bb) * SCL);
  } else if (kind == 1) {
    #pragma unroll
    for (int r = 0; r < 8; ++r)
      kb[(size_t)(row0 + r) * 64 + c0 + col] = f2bf(acc[r] + bb);
  } else {
    const int rl = (tid >> 5) * 8;
    #pragma unroll
    for (int r = 0; r < 8; ++r) Ts[col][rl + r] = acc[r] + bb;
    __syncthreads();
    const int c = tid >> 3, rr = (tid & 7) * 8;
    short8 pk;
    #pragma unroll
    for (int j = 0; j < 8; ++j) pk[j] = (short)f2bf(Ts[c][rr + j]);
    *(short8*)(Vt + (size_t)(c0 + c) * NN + blockIdx.x * 64 + rr) = pk;
  }
}

// ---------------- fused attention: l-loop, then P/attn/O loop ----------------
// grid 512 x 1024 threads (16 waves). Wave strip = 512 keys -> 16 iters/loop.
// 2 blocks/CU x 16 waves = 32 waves/CU (full occupancy) for latency hiding.
__global__ __launch_bounds__(1024, 8) void att_fused(
    const unsigned short* __restrict__ qb, const unsigned short* __restrict__ kb,
    const unsigned short* __restrict__ Vt,
    float* __restrict__ attn, float* __restrict__ O) {
  __shared__ __align__(16) float Esh[16][2][16 * 36];  // per-wave P staging [16q x 32k, stride 36]
  __shared__ float lsh[16][16][2];
  __shared__ float Osh[16 * 64];
  const int tid = threadIdx.x;
  const int lane = tid & 63, wv = tid >> 6;
  const int ql = lane & 15, quad = lane >> 4;
  const int qt0 = blockIdx.x * 16;
  const floatx4 zf = {0.f, 0.f, 0.f, 0.f};

  for (int idx = tid; idx < 16 * 64; idx += 1024) Osh[idx] = 0.f;

  short8 qf[2];
  #pragma unroll
  for (int h = 0; h < 2; ++h)
    qf[h] = *(const short8*)(qb + (size_t)(qt0 + ql) * 64 + h * 32 + quad * 8);

  // ---- loop 1: row sums ----
  float lacc[2][4];
  #pragma unroll
  for (int h = 0; h < 2; ++h)
    #pragma unroll
    for (int r = 0; r < 4; ++r) lacc[h][r] = 0.f;
  int kbase = wv * 512;
  for (int it = 0; it < 16; ++it, kbase += 32) {
    short8 kf[2][2];
    #pragma unroll
    for (int kt = 0; kt < 2; ++kt)
      #pragma unroll
      for (int h = 0; h < 2; ++h)
        kf[kt][h] = *(const short8*)(kb + (size_t)(kbase + kt * 16 + ql) * 64 + h * 32 + quad * 8);
    #pragma unroll
    for (int h = 0; h < 2; ++h)
      #pragma unroll
      for (int kt = 0; kt < 2; ++kt) {
        floatx4 s = __builtin_amdgcn_mfma_f32_16x16x32_bf16(qf[h], kf[kt][h], zf, 0, 0, 0);
        #pragma unroll
        for (int r = 0; r < 4; ++r) lacc[h][r] += __builtin_amdgcn_exp2f(s[r]);
      }
  }
  #pragma unroll
  for (int o = 8; o >= 1; o >>= 1)
    #pragma unroll
    for (int h = 0; h < 2; ++h)
      #pragma unroll
      for (int r = 0; r < 4; ++r)
        lacc[h][r] += __shfl_xor(lacc[h][r], o, 16);
  if (ql == 0) {
    #pragma unroll
    for (int h = 0; h < 2; ++h)
      #pragma unroll
      for (int r = 0; r < 4; ++r)
        lsh[wv][quad * 4 + r][h] = lacc[h][r];
  }
  __syncthreads();
  float invl[2][4];
  #pragma unroll
  for (int h = 0; h < 2; ++h)
    #pragma unroll
    for (int r = 0; r < 4; ++r) {
      int row = quad * 4 + r;
      float s = 0.f;
      #pragma unroll
      for (int w = 0; w < 16; ++w) s += lsh[w][row][h];
      invl[h][r] = 1.0f / s;
    }

  // ---- loop 2: P, attn writes (dwordx4 full lines), PV ----
  floatx4 oacc[2][2];
  #pragma unroll
  for (int h = 0; h < 2; ++h)
    #pragma unroll
    for (int hf = 0; hf < 2; ++hf) oacc[h][hf] = zf;

  const int r8 = lane >> 3;            // 0..7 row within half-tile
  const int c4 = (lane & 7) * 4;       // 0..28 col group
  kbase = wv * 512;
  for (int it = 0; it < 16; ++it, kbase += 32) {
    short8 kf[2][2], vf[2][2];
    #pragma unroll
    for (int kt = 0; kt < 2; ++kt)
      #pragma unroll
      for (int h = 0; h < 2; ++h)
        kf[kt][h] = *(const short8*)(kb + (size_t)(kbase + kt * 16 + ql) * 64 + h * 32 + quad * 8);
    #pragma unroll
    for (int h = 0; h < 2; ++h)
      #pragma unroll
      for (int hf = 0; hf < 2; ++hf)
        vf[h][hf] = *(const short8*)(Vt + (size_t)(h * 32 + hf * 16 + ql) * NN + kbase + quad * 8);

    floatx4 p[2][2];  // [head][kt]
    #pragma unroll
    for (int h = 0; h < 2; ++h)
      #pragma unroll
      for (int kt = 0; kt < 2; ++kt) {
        floatx4 s = __builtin_amdgcn_mfma_f32_16x16x32_bf16(qf[h], kf[kt][h], zf, 0, 0, 0);
        #pragma unroll
        for (int r = 0; r < 4; ++r)
          p[h][kt][r] = __builtin_amdgcn_exp2f(s[r]) * invl[h][r];
      }
    // C-layout -> LDS (per-wave staging)
    #pragma unroll
    for (int h = 0; h < 2; ++h)
      #pragma unroll
      for (int kt = 0; kt < 2; ++kt)
        #pragma unroll
        for (int r = 0; r < 4; ++r)
          Esh[wv][h][(quad * 4 + r) * 36 + kt * 16 + ql] = p[h][kt][r];
    // attn head-mean: row-major readback, full-cache-line dwordx4 stores
    {
      const float4 a0 = *(const float4*)&Esh[wv][0][r8 * 36 + c4];
      const float4 b0 = *(const float4*)&Esh[wv][1][r8 * 36 + c4];
      const float4 a1 = *(const float4*)&Esh[wv][0][(r8 + 8) * 36 + c4];
      const float4 b1 = *(const float4*)&Esh[wv][1][(r8 + 8) * 36 + c4];
      float4 m0, m1;
      m0.x = 0.5f * (a0.x + b0.x); m0.y = 0.5f * (a0.y + b0.y);
      m0.z = 0.5f * (a0.z + b0.z); m0.w = 0.5f * (a0.w + b0.w);
      m1.x = 0.5f * (a1.x + b1.x); m1.y = 0.5f * (a1.y + b1.y);
      m1.z = 0.5f * (a1.z + b1.z); m1.w = 0.5f * (a1.w + b1.w);
      *(float4*)&attn[(size_t)(qt0 + r8) * NN + kbase + c4] = m0;
      *(float4*)&attn[(size_t)(qt0 + r8 + 8) * NN + kbase + c4] = m1;
    }
    // LDS -> A-layout, PV mfma
    #pragma unroll
    for (int h = 0; h < 2; ++h) {
      const float* ep = &Esh[wv][h][ql * 36 + quad * 8];
      float4 x0 = *(const float4*)ep;
      float4 x1 = *(const float4*)(ep + 4);
      short8 ef;
      ef[0] = (short)f2bf(x0.x); ef[1] = (short)f2bf(x0.y);
      ef[2] = (short)f2bf(x0.z); ef[3] = (short)f2bf(x0.w);
      ef[4] = (short)f2bf(x1.x); ef[5] = (short)f2bf(x1.y);
      ef[6] = (short)f2bf(x1.z); ef[7] = (short)f2bf(x1.w);
      #pragma unroll
      for (int hf = 0; hf < 2; ++hf)
        oacc[h][hf] = __builtin_amdgcn_mfma_f32_16x16x32_bf16(ef, vf[h][hf], oacc[h][hf], 0, 0, 0);
    }
  }
  #pragma unroll
  for (int h = 0; h < 2; ++h)
    #pragma unroll
    for (int hf = 0; hf < 2; ++hf)
      #pragma unroll
      for (int r = 0; r < 4; ++r)
        atomicAdd(&Osh[(quad * 4 + r) * 64 + h * 32 + hf * 16 + ql], oacc[h][hf][r]);
  __syncthreads();
  for (int idx = tid; idx < 16 * 64; idx += 1024)
    O[(size_t)qt0 * 64 + idx] = Osh[idx];
}

// ---------------- tail: h_attn=O@Wo+bo ; y1=relu([htkg|h_attn]@fc1+b) ; pred=y1@fc2+b ----
__global__ __launch_bounds__(256) void tail_k(const float* __restrict__ O,
    const float* __restrict__ htkg, const float* __restrict__ Wo, const float* __restrict__ bo,
    const float* __restrict__ fc1W, const float* __restrict__ fc1b,
    const float* __restrict__ fc2W, const float* __restrict__ fc2b,
    float* __restrict__ pred) {
  __shared__ float Ws[8192];
  __shared__ float T1[2048];
  __shared__ float T2[2048];
  const int tid = threadIdx.x;
  const int col = tid & 63, rg = tid >> 6;
  const int rowbase = blockIdx.x * 32;
  for (int i = tid; i < 2048; i += 256) T1[i] = O[(size_t)rowbase * 64 + i];
  for (int i = tid; i < 4096; i += 256) Ws[i] = Wo[i];
  const float rbo = bo[col], rf1b = fc1b[col], rf2 = fc2W[col], rf2b = fc2b[0];
  __syncthreads();
  float ha[8];
  #pragma unroll
  for (int r = 0; r < 8; ++r) {
    const int row = rg * 8 + r;
    float acc = rbo;
    for (int k = 0; k < 64; ++k) acc = fmaf(T1[row * 64 + k], Ws[k * 64 + col], acc);
    ha[r] = acc;
  }
  __syncthreads();
  #pragma unroll
  for (int r = 0; r < 8; ++r) T2[(rg * 8 + r) * 64 + col] = ha[r];
  for (int i = tid; i < 2048; i += 256) T1[i] = htkg[(size_t)rowbase * 64 + i];
  for (int i = tid; i < 8192; i += 256) Ws[i] = fc1W[i];
  __syncthreads();
  #pragma unroll
  for (int r = 0; r < 8; ++r) {
    const int row = rg * 8 + r;
    float acc = rf1b;
    for (int k = 0; k < 64; ++k) acc = fmaf(T1[row * 64 + k], Ws[k * 64 + col], acc);
    for (int k = 0; k < 64; ++k) acc = fmaf(T2[row * 64 + k], Ws[(64 + k) * 64 + col], acc);
    float y = fmaxf(acc, 0.f);
    float v = y * rf2;
    #pragma unroll
    for (int m = 32; m >= 1; m >>= 1) v += __shfl_xor(v, m);
    if (col == 0) pred[rowbase + row] = v + rf2b;
  }
}

extern "C" void kernel_launch(void* const* d_in, const int* in_sizes, int n_in,
                              void* d_out, int out_size, void* d_ws, size_t ws_size,
                              hipStream_t stream) {
  (void)in_sizes; (void)n_in; (void)out_size; (void)ws_size;
  const float* x       = (const float*)d_in[0];
  const int*   ei_t    = (const int*)d_in[1];
  const int*   ei_e    = (const int*)d_in[2];
  const float* gat1_W  = (const float*)d_in[3];
  const float* gat1_as = (const float*)d_in[4];
  const float* gat1_ad = (const float*)d_in[5];
  const float* gat1_b  = (const float*)d_in[6];
  const float* gat2_W  = (const float*)d_in[7];
  const float* gat2_as = (const float*)d_in[8];
  const float* gat2_ad = (const float*)d_in[9];
  const float* gat2_b  = (const float*)d_in[10];
  const float* gcn1_W  = (const float*)d_in[11];
  const float* gcn1_b  = (const float*)d_in[12];
  const float* gcn2_W  = (const float*)d_in[13];
  const float* gcn2_b  = (const float*)d_in[14];
  const float* Wq = (const float*)d_in[15]; const float* bq = (const float*)d_in[16];
  const float* Wk = (const float*)d_in[17]; const float* bk = (const float*)d_in[18];
  const float* Wv = (const float*)d_in[19]; const float* bv = (const float*)d_in[20];
  const float* Wo = (const float*)d_in[21]; const float* bo = (const float*)d_in[22];
  const float* fc1_W = (const float*)d_in[23]; const float* fc1_b = (const float*)d_in[24];
  const float* fc2_W = (const float*)d_in[25]; const float* fc2_b = (const float*)d_in[26];

  float* out  = (float*)d_out;
  float* attn = out + NN;   // [N, N] fp32, after pred[N]

  char* wsp = (char*)d_ws;
  size_t ofs = 0;
  auto take = [&](size_t bytes) -> char* {
    char* p = wsp + ofs;
    ofs = (ofs + bytes + 255) & ~(size_t)255;
    return p;
  };
  // ---- contiguous zero-init region first (single memset) ----
  int*   pos_t = (int*)take(NN * 4);
  int*   pos_e = (int*)take(NN * 4);
  float* a_s1  = (float*)take((size_t)NN * 2 * 4);
  float* a_d1  = (float*)take((size_t)NN * 2 * 4);
  float* a_s2  = (float*)take((size_t)NN * 4);
  float* a_d2  = (float*)take((size_t)NN * 4);
  const size_t zero_span = ofs;
  // ---- rest ----
  int* off_t = (int*)take((NN + 1) * 4);
  int* off_e = (int*)take((NN + 1) * 4);
  int* src_t = (int*)take((size_t)ET * 4);
  int* src_e = (int*)take((size_t)ET * 4);
  float* h1    = (float*)take((size_t)NN * 128 * 4);
  float* g1out = (float*)take((size_t)NN * 128 * 4);
  float* h2    = (float*)take((size_t)NN * 64 * 4);
  float* htkg  = (float*)take((size_t)NN * 64 * 4);
  float* hg1   = (float*)take((size_t)NN * 64 * 4);
  float* h2g   = (float*)take((size_t)NN * 64 * 4);
  float* hekg  = (float*)take((size_t)NN * 64 * 4);
  unsigned short* qb = (unsigned short*)take((size_t)NN * 64 * 2);
  unsigned short* kb = (unsigned short*)take((size_t)NN * 64 * 2);
  unsigned short* Vt = (unsigned short*)take((size_t)64 * NN * 2);
  float* Obuf  = (float*)take((size_t)NN * 64 * 4);

  hipMemsetAsync(wsp, 0, zero_span, stream);

  // CSR for both graphs
  edge_hist2_k<<<2 * ET / 256, 256, 0, stream>>>(ei_t, ei_e, pos_t, pos_e);
  scan2_k<<<2, 1024, 0, stream>>>(pos_t, off_t, pos_e, off_e);
  edge_scatter2_k<<<2 * ET / 256, 256, 0, stream>>>(ei_t, ei_e, pos_t, pos_e, src_t, src_e);

  // x projections for both branches + gat1 att_sd epilogue
  mm_x_k<<<dim3(128, 6), 256, 0, stream>>>(x, gat1_W, gcn1_W, gat1_as, gat1_ad,
                                           h1, hg1, a_s1, a_d1);
  // merged gat1-agg + gcn1-agg+gemv
  agg1_k<<<NN + NN / 2, 128, 0, stream>>>(h1, a_s1, a_d1, off_t, src_t, gat1_b, g1out,
                                          hg1, off_e, src_e, gcn1_b, gcn2_W, h2g);
  // merged mm_gat2 + gcn_agg2
  mm2_k<<<256 + NN / 4, 256, 0, stream>>>(g1out, gat2_W, gat2_as, gat2_ad, h2, a_s2, a_d2,
                                          h2g, off_e, src_e, gcn2_b, hekg);
  // gat layer-2 aggregation
  gat_agg_k<1, 64><<<NN, 64, 0, stream>>>(h2, a_s2, a_d2, off_t, src_t, gat2_b, htkg, 64);

  // qkv projections + V transpose
  mm_qkv_k<<<dim3(128, 6), 256, 0, stream>>>(htkg, hekg, Wq, bq, Wk, bk, Wv, bv, qb, kb, Vt);

  // fused attention: 16 waves/block -> 32 waves/CU for latency hiding
  att_fused<<<512, 1024, 0, stream>>>(qb, kb, Vt, attn, Obuf);

  // fused epilogue: Wo + fc1 + fc2
  tail_k<<<256, 256, 0, stream>>>(Obuf, htkg, Wo, bo, fc1_W, fc1_b, fc2_W, fc2_b, out);
}

// Round 3
// 691.580 us; speedup vs baseline: 1.0862x; 1.0862x over previous
//
#include <hip/hip_runtime.h>
#include <cstdint>
#include <cstddef>

#define NN 8192
#define EE 262144
#define ET 270336   // EE + NN self loops

using short8  = __attribute__((ext_vector_type(8))) short;
using floatx4 = __attribute__((ext_vector_type(4))) float;

__device__ __forceinline__ unsigned short f2bf(float f) {
  unsigned int u = __float_as_uint(f);
  u += 0x7fffu + ((u >> 16) & 1u);          // RNE
  return (unsigned short)(u >> 16);
}

// ---------------- CSR build, both graphs in one launch ----------------
__global__ void edge_hist2_k(const int* __restrict__ ei_t, const int* __restrict__ ei_e,
                             int* __restrict__ cnt_t, int* __restrict__ cnt_e) {
  int idx = blockIdx.x * 256 + threadIdx.x;
  int g = idx >= ET;                        // block-uniform (ET % 256 == 0)
  int e = g ? idx - ET : idx;
  const int* ei = g ? ei_e : ei_t;
  int* cnt = g ? cnt_e : cnt_t;
  int d = (e < EE) ? ei[EE + e] : (e - EE);
  atomicAdd(&cnt[d], 1);
}

__global__ void scan2_k(int* cnt_t, int* off_t, int* cnt_e, int* off_e) {
  int* cnt = blockIdx.x ? cnt_e : cnt_t;    // pos aliases cnt (overwritten)
  int* off = blockIdx.x ? off_e : off_t;
  __shared__ int s[1024];
  int t = threadIdx.x;
  int v[8]; int base = t * 8; int sum = 0;
  #pragma unroll
  for (int j = 0; j < 8; ++j) { v[j] = cnt[base + j]; sum += v[j]; }
  s[t] = sum; __syncthreads();
  for (int o = 1; o < 1024; o <<= 1) {
    int x = (t >= o) ? s[t - o] : 0;
    __syncthreads();
    s[t] += x;
    __syncthreads();
  }
  int excl = s[t] - sum;
  #pragma unroll
  for (int j = 0; j < 8; ++j) { off[base + j] = excl; cnt[base + j] = excl; excl += v[j]; }
  if (t == 1023) off[NN] = excl;
}

__global__ void edge_scatter2_k(const int* __restrict__ ei_t, const int* __restrict__ ei_e,
                                int* __restrict__ pos_t, int* __restrict__ pos_e,
                                int* __restrict__ srcs_t, int* __restrict__ srcs_e) {
  int idx = blockIdx.x * 256 + threadIdx.x;
  int g = idx >= ET;
  int e = g ? idx - ET : idx;
  const int* ei = g ? ei_e : ei_t;
  int* pos = g ? pos_e : pos_t;
  int* srcs = g ? srcs_e : srcs_t;
  int sv, d;
  if (e < EE) { sv = ei[e]; d = ei[EE + e]; } else { sv = d = e - EE; }
  int p = atomicAdd(&pos[d], 1);
  srcs[p] = sv;
}

// ---------------- shared GEMM inner loop ----------------
__device__ __forceinline__ void gemm_core(const float* __restrict__ A, int lda, int K,
                                          const float* __restrict__ Bs, int row0, int col,
                                          float acc[8]) {
  #pragma unroll
  for (int r = 0; r < 8; ++r) acc[r] = 0.f;
  for (int k = 0; k < K; k += 4) {
    float b0 = Bs[(k + 0) * 32 + col], b1 = Bs[(k + 1) * 32 + col];
    float b2 = Bs[(k + 2) * 32 + col], b3 = Bs[(k + 3) * 32 + col];
    #pragma unroll
    for (int r = 0; r < 8; ++r) {
      const float4 a4 = *(const float4*)(A + (size_t)(row0 + r) * lda + k);
      acc[r] = fmaf(a4.x, b0, acc[r]);
      acc[r] = fmaf(a4.y, b1, acc[r]);
      acc[r] = fmaf(a4.z, b2, acc[r]);
      acc[r] = fmaf(a4.w, b3, acc[r]);
    }
  }
}

// ---------------- mm_x: h1 = x@gat1_W (+att_sd epilogue), hg1 = x@gcn1_W ----------------
__global__ __launch_bounds__(256) void mm_x_k(const float* __restrict__ x,
    const float* __restrict__ Wgat, const float* __restrict__ Wgcn,
    const float* __restrict__ as_w, const float* __restrict__ ad_w,
    float* __restrict__ h1, float* __restrict__ hg1,
    float* __restrict__ a_s1, float* __restrict__ a_d1) {
  __shared__ float Bs[256 * 32];
  const int tid = threadIdx.x, by = blockIdx.y;
  const bool gat = by < 4;
  const int NC = gat ? 128 : 64;
  const int c0 = gat ? by * 32 : (by - 4) * 32;
  const float* B = gat ? Wgat : Wgcn;
  for (int idx = tid; idx < 256 * 32; idx += 256)
    Bs[idx] = B[(idx >> 5) * NC + c0 + (idx & 31)];
  __syncthreads();
  const int row0 = blockIdx.x * 64 + (tid >> 5) * 8;
  const int col = tid & 31;
  float acc[8];
  gemm_core(x, 256, 256, Bs, row0, col, acc);
  if (gat) {
    #pragma unroll
    for (int r = 0; r < 8; ++r) h1[(size_t)(row0 + r) * 128 + c0 + col] = acc[r];
    const int head = c0 >> 6;
    const float asw = as_w[head * 64 + (c0 & 63) + col];
    const float adw = ad_w[head * 64 + (c0 & 63) + col];
    float ps[8], pd[8];
    #pragma unroll
    for (int r = 0; r < 8; ++r) { ps[r] = acc[r] * asw; pd[r] = acc[r] * adw; }
    #pragma unroll
    for (int m = 16; m >= 1; m >>= 1)
      #pragma unroll
      for (int r = 0; r < 8; ++r) { ps[r] += __shfl_xor(ps[r], m); pd[r] += __shfl_xor(pd[r], m); }
    if (col == 0) {
      #pragma unroll
      for (int r = 0; r < 8; ++r) {
        atomicAdd(&a_s1[(row0 + r) * 2 + head], ps[r]);
        atomicAdd(&a_d1[(row0 + r) * 2 + head], pd[r]);
      }
    }
  } else {
    #pragma unroll
    for (int r = 0; r < 8; ++r) hg1[(size_t)(row0 + r) * 64 + c0 + col] = acc[r];
  }
}

// ---------------- GAT aggregation ----------------
template<int H, int C>
__device__ __forceinline__ void gat_agg_body(const float* __restrict__ h,
    const float* __restrict__ a_s, const float* __restrict__ a_d,
    const int* __restrict__ off, const int* __restrict__ srcs,
    const float* __restrict__ bias, float* __restrict__ out, int ldout, int b) {
  constexpr int HC = H * C;
  const int tid = threadIdx.x;
  const int hd = tid / C;
  const int r0 = off[b], r1 = off[b + 1];
  __shared__ int s_src[HC];
  __shared__ float s_w[HC][H];
  float ad[H];
  #pragma unroll
  for (int hh = 0; hh < H; ++hh) ad[hh] = a_d[b * H + hh];
  float acc = 0.f, den = 0.f;
  for (int base = r0; base < r1; base += HC) {
    __syncthreads();
    int e = base + tid;
    if (e < r1) {
      int sv = srcs[e];
      s_src[tid] = sv;
      #pragma unroll
      for (int hh = 0; hh < H; ++hh) {
        float xv = a_s[sv * H + hh] + ad[hh];
        xv = xv > 0.f ? xv : 0.2f * xv;     // leaky_relu 0.2
        s_w[tid][hh] = __expf(xv);
      }
    }
    __syncthreads();
    int cnt = min(HC, r1 - base);
    for (int j = 0; j < cnt; ++j) {
      float wv = s_w[j][hd];
      den += wv;
      acc = fmaf(wv, h[(size_t)s_src[j] * HC + tid], acc);
    }
  }
  float o = acc / den + bias[tid];
  out[(size_t)b * ldout + tid] = o > 0.f ? o : (__expf(o) - 1.f);  // elu
}

template<int H, int C>
__global__ void gat_agg_k(const float* __restrict__ h, const float* __restrict__ a_s,
                          const float* __restrict__ a_d, const int* __restrict__ off,
                          const int* __restrict__ srcs, const float* __restrict__ bias,
                          float* __restrict__ out, int ldout) {
  gat_agg_body<H, C>(h, a_s, a_d, off, srcs, bias, out, ldout, blockIdx.x);
}

// ---------------- merged: gat1 aggregation (blocks 0..NN) + gcn1 agg+gemv (2 nodes/blk) ----
__global__ __launch_bounds__(128) void agg1_k(
    const float* __restrict__ h1, const float* __restrict__ a_s1, const float* __restrict__ a_d1,
    const int* __restrict__ off_t, const int* __restrict__ src_t,
    const float* __restrict__ gat1_b, float* __restrict__ g1out,
    const float* __restrict__ hg1, const int* __restrict__ off_e, const int* __restrict__ src_e,
    const float* __restrict__ gcn1_b, const float* __restrict__ gcn2_W, float* __restrict__ h2g) {
  const int tid = threadIdx.x;
  if (blockIdx.x < NN) {
    gat_agg_body<2, 64>(h1, a_s1, a_d1, off_t, src_t, gat1_b, g1out, 128, blockIdx.x);
  } else {
    const int nb = (blockIdx.x - NN) * 2;
    const int sub = tid >> 6, t = tid & 63;
    const int node = nb + sub;
    __shared__ int s_src2[2][64];
    __shared__ float s_nrm2[2][64];
    __shared__ float s_row2[2][64];
    const int r0 = off_e[node], r1 = off_e[node + 1];
    const int cA = off_e[nb + 1] - off_e[nb];
    const int cB = off_e[nb + 2] - off_e[nb + 1];
    const int trips = (max(cA, cB) + 63) >> 6;
    float dinv_b = rsqrtf((float)max(r1 - r0, 1));
    float acc = 0.f;
    for (int it = 0; it < trips; ++it) {
      __syncthreads();
      int e = r0 + it * 64 + t;
      if (e < r1) {
        int sv = src_e[e];
        s_src2[sub][t] = sv;
        int ds = off_e[sv + 1] - off_e[sv];
        s_nrm2[sub][t] = dinv_b * rsqrtf((float)max(ds, 1));
      }
      __syncthreads();
      int cnt = min(64, r1 - (r0 + it * 64));
      for (int j = 0; j < cnt; ++j)
        acc = fmaf(s_nrm2[sub][j], hg1[(size_t)s_src2[sub][j] * 64 + t], acc);
    }
    s_row2[sub][t] = fmaxf(acc + gcn1_b[t], 0.f);
    __syncthreads();
    float acc2 = 0.f;
    for (int k = 0; k < 64; ++k)
      acc2 = fmaf(s_row2[sub][k], gcn2_W[k * 64 + t], acc2);
    h2g[(size_t)node * 64 + t] = acc2;
  }
}

// ---------------- merged: mm_gat2 (blocks 0..256) + gcn_agg2 (4 nodes/blk) ----------------
__global__ __launch_bounds__(256) void mm2_k(
    const float* __restrict__ g1out, const float* __restrict__ gat2_W,
    const float* __restrict__ gat2_as, const float* __restrict__ gat2_ad,
    float* __restrict__ h2, float* __restrict__ a_s2, float* __restrict__ a_d2,
    const float* __restrict__ h2g, const int* __restrict__ off_e, const int* __restrict__ src_e,
    const float* __restrict__ gcn2_b, float* __restrict__ hekg) {
  const int tid = threadIdx.x;
  if (blockIdx.x < 256) {
    __shared__ float Bs[128 * 32];
    const int bx = blockIdx.x & 127;
    const int c0 = (blockIdx.x >> 7) * 32;
    for (int idx = tid; idx < 128 * 32; idx += 256)
      Bs[idx] = gat2_W[(idx >> 5) * 64 + c0 + (idx & 31)];
    __syncthreads();
    const int row0 = bx * 64 + (tid >> 5) * 8;
    const int col = tid & 31;
    float acc[8];
    gemm_core(g1out, 128, 128, Bs, row0, col, acc);
    const float asw = gat2_as[c0 + col];
    const float adw = gat2_ad[c0 + col];
    float ps[8], pd[8];
    #pragma unroll
    for (int r = 0; r < 8; ++r) {
      h2[(size_t)(row0 + r) * 64 + c0 + col] = acc[r];
      ps[r] = acc[r] * asw; pd[r] = acc[r] * adw;
    }
    #pragma unroll
    for (int m = 16; m >= 1; m >>= 1)
      #pragma unroll
      for (int r = 0; r < 8; ++r) { ps[r] += __shfl_xor(ps[r], m); pd[r] += __shfl_xor(pd[r], m); }
    if (col == 0) {
      #pragma unroll
      for (int r = 0; r < 8; ++r) {
        atomicAdd(&a_s2[row0 + r], ps[r]);
        atomicAdd(&a_d2[row0 + r], pd[r]);
      }
    }
  } else {
    const int nb = (blockIdx.x - 256) * 4;
    const int sub = tid >> 6, t = tid & 63;
    const int node = nb + sub;
    __shared__ int s_src4[4][64];
    __shared__ float s_nrm4[4][64];
    const int r0 = off_e[node], r1 = off_e[node + 1];
    int cmax = 0;
    #pragma unroll
    for (int i = 0; i < 4; ++i) cmax = max(cmax, off_e[nb + i + 1] - off_e[nb + i]);
    const int trips = (cmax + 63) >> 6;
    float dinv_b = rsqrtf((float)max(r1 - r0, 1));
    float acc = 0.f;
    for (int it = 0; it < trips; ++it) {
      __syncthreads();
      int e = r0 + it * 64 + t;
      if (e < r1) {
        int sv = src_e[e];
        s_src4[sub][t] = sv;
        int ds = off_e[sv + 1] - off_e[sv];
        s_nrm4[sub][t] = dinv_b * rsqrtf((float)max(ds, 1));
      }
      __syncthreads();
      int cnt = min(64, r1 - (r0 + it * 64));
      for (int j = 0; j < cnt; ++j)
        acc = fmaf(s_nrm4[sub][j], h2g[(size_t)s_src4[sub][j] * 64 + t], acc);
    }
    hekg[(size_t)node * 64 + t] = fmaxf(acc + gcn2_b[t], 0.f);
  }
}

// ---------------- qkv projections (+V transpose) ----------------
__global__ __launch_bounds__(256) void mm_qkv_k(const float* __restrict__ htkg,
    const float* __restrict__ hekg,
    const float* __restrict__ Wq, const float* __restrict__ bq,
    const float* __restrict__ Wk, const float* __restrict__ bk,
    const float* __restrict__ Wv, const float* __restrict__ bv,
    unsigned short* __restrict__ qb, unsigned short* __restrict__ kb,
    unsigned short* __restrict__ Vt) {
  __shared__ float Bs[64 * 32];
  __shared__ float Ts[32][65];
  const int tid = threadIdx.x, by = blockIdx.y;
  const int kind = by >> 1;
  const int c0 = (by & 1) * 32;
  const float* A = (kind == 0) ? htkg : hekg;
  const float* B = (kind == 0) ? Wq : (kind == 1) ? Wk : Wv;
  const float* bias = (kind == 0) ? bq : (kind == 1) ? bk : bv;
  for (int idx = tid; idx < 64 * 32; idx += 256)
    Bs[idx] = B[(idx >> 5) * 64 + c0 + (idx & 31)];
  __syncthreads();
  const int row0 = blockIdx.x * 64 + (tid >> 5) * 8;
  const int col = tid & 31;
  float acc[8];
  gemm_core(A, 64, 64, Bs, row0, col, acc);
  const float bb = bias[c0 + col];
  if (kind == 0) {
    const float SCL = 0.17677669529663687f * 1.4426950408889634f;  // 1/sqrt(32) * log2(e)
    #pragma unroll
    for (int r = 0; r < 8; ++r)
      qb[(size_t)(row0 + r) * 64 + c0 + col] = f2bf((acc[r] + bb) * SCL);
  } else if (kind == 1) {
    #pragma unroll
    for (int r = 0; r < 8; ++r)
      kb[(size_t)(row0 + r) * 64 + c0 + col] = f2bf(acc[r] + bb);
  } else {
    const int rl = (tid >> 5) * 8;
    #pragma unroll
    for (int r = 0; r < 8; ++r) Ts[col][rl + r] = acc[r] + bb;
    __syncthreads();
    const int c = tid >> 3, rr = (tid & 7) * 8;
    short8 pk;
    #pragma unroll
    for (int j = 0; j < 8; ++j) pk[j] = (short)f2bf(Ts[c][rr + j]);
    *(short8*)(Vt + (size_t)(c0 + c) * NN + blockIdx.x * 64 + rr) = pk;
  }
}

// ---------------- fused attention: l-loop, then P/attn/O loop ----------------
// grid 512 x 512 threads (8 waves). Wave strip = 1024 keys.
// Loop 2 processes 64 keys/iteration (two 32-key sub-steps) so each attn row
// write is a full 256-B line -> no half-line L2 merge pressure at high wave
// counts (rounds 1/2 regression: 512-key strips left 32 MB of half-written
// lines open -> eviction -> 2.2x write traffic + write-allocate refetch).
__global__ __launch_bounds__(512, 4) void att_fused(
    const unsigned short* __restrict__ qb, const unsigned short* __restrict__ kb,
    const unsigned short* __restrict__ Vt,
    float* __restrict__ attn, float* __restrict__ O) {
  __shared__ __align__(16) float Esh[8][2][2][16 * 36]; // [wave][head][ks32][16q x 32k pad36]
  __shared__ float lsh[8][16][2];
  __shared__ float Osh[16 * 64];
  const int tid = threadIdx.x;
  const int lane = tid & 63, wv = tid >> 6;
  const int ql = lane & 15, quad = lane >> 4;
  const int qt0 = blockIdx.x * 16;
  const floatx4 zf = {0.f, 0.f, 0.f, 0.f};

  for (int idx = tid; idx < 16 * 64; idx += 512) Osh[idx] = 0.f;

  short8 qf[2];
  #pragma unroll
  for (int h = 0; h < 2; ++h)
    qf[h] = *(const short8*)(qb + (size_t)(qt0 + ql) * 64 + h * 32 + quad * 8);

  // ---- loop 1: row sums (32-key steps over 1024-key strip) ----
  float lacc[2][4];
  #pragma unroll
  for (int h = 0; h < 2; ++h)
    #pragma unroll
    for (int r = 0; r < 4; ++r) lacc[h][r] = 0.f;
  int kbase = wv * 1024;
  for (int it = 0; it < 32; ++it, kbase += 32) {
    short8 kf[2][2];
    #pragma unroll
    for (int kt = 0; kt < 2; ++kt)
      #pragma unroll
      for (int h = 0; h < 2; ++h)
        kf[kt][h] = *(const short8*)(kb + (size_t)(kbase + kt * 16 + ql) * 64 + h * 32 + quad * 8);
    #pragma unroll
    for (int h = 0; h < 2; ++h)
      #pragma unroll
      for (int kt = 0; kt < 2; ++kt) {
        floatx4 s = __builtin_amdgcn_mfma_f32_16x16x32_bf16(qf[h], kf[kt][h], zf, 0, 0, 0);
        #pragma unroll
        for (int r = 0; r < 4; ++r) lacc[h][r] += __builtin_amdgcn_exp2f(s[r]);
      }
  }
  #pragma unroll
  for (int o = 8; o >= 1; o >>= 1)
    #pragma unroll
    for (int h = 0; h < 2; ++h)
      #pragma unroll
      for (int r = 0; r < 4; ++r)
        lacc[h][r] += __shfl_xor(lacc[h][r], o, 16);
  if (ql == 0) {
    #pragma unroll
    for (int h = 0; h < 2; ++h)
      #pragma unroll
      for (int r = 0; r < 4; ++r)
        lsh[wv][quad * 4 + r][h] = lacc[h][r];
  }
  __syncthreads();
  float invl[2][4];
  #pragma unroll
  for (int h = 0; h < 2; ++h)
    #pragma unroll
    for (int r = 0; r < 4; ++r) {
      int row = quad * 4 + r;
      float s = 0.f;
      #pragma unroll
      for (int w = 0; w < 8; ++w) s += lsh[w][row][h];
      invl[h][r] = 1.0f / s;
    }

  // ---- loop 2: 64 keys/iter = two 32-key sub-steps, then full-line attn write ----
  floatx4 oacc[2][2];
  #pragma unroll
  for (int h = 0; h < 2; ++h)
    #pragma unroll
    for (int hf = 0; hf < 2; ++hf) oacc[h][hf] = zf;

  const int rrow = lane >> 2;          // 0..15: attn row handled on readback
  const int cq   = lane & 3;           // 0..3: 16-float quarter of the 64-col stripe
  kbase = wv * 1024;
  for (int it = 0; it < 16; ++it, kbase += 64) {
    #pragma unroll
    for (int ks = 0; ks < 2; ++ks) {
      const int kb32 = kbase + ks * 32;
      short8 kf[2][2], vf[2][2];
      #pragma unroll
      for (int kt = 0; kt < 2; ++kt)
        #pragma unroll
        for (int h = 0; h < 2; ++h)
          kf[kt][h] = *(const short8*)(kb + (size_t)(kb32 + kt * 16 + ql) * 64 + h * 32 + quad * 8);
      #pragma unroll
      for (int h = 0; h < 2; ++h)
        #pragma unroll
        for (int hf = 0; hf < 2; ++hf)
          vf[h][hf] = *(const short8*)(Vt + (size_t)(h * 32 + hf * 16 + ql) * NN + kb32 + quad * 8);

      // QK^T, exp2, normalize -> LDS (C-layout, per-wave staging)
      #pragma unroll
      for (int h = 0; h < 2; ++h)
        #pragma unroll
        for (int kt = 0; kt < 2; ++kt) {
          floatx4 s = __builtin_amdgcn_mfma_f32_16x16x32_bf16(qf[h], kf[kt][h], zf, 0, 0, 0);
          #pragma unroll
          for (int r = 0; r < 4; ++r)
            Esh[wv][h][ks][(quad * 4 + r) * 36 + kt * 16 + ql] =
                __builtin_amdgcn_exp2f(s[r]) * invl[h][r];
        }
      // LDS -> A-layout, PV mfma for this 32-key half
      #pragma unroll
      for (int h = 0; h < 2; ++h) {
        const float* ep = &Esh[wv][h][ks][ql * 36 + quad * 8];
        float4 x0 = *(const float4*)ep;
        float4 x1 = *(const float4*)(ep + 4);
        short8 ef;
        ef[0] = (short)f2bf(x0.x); ef[1] = (short)f2bf(x0.y);
        ef[2] = (short)f2bf(x0.z); ef[3] = (short)f2bf(x0.w);
        ef[4] = (short)f2bf(x1.x); ef[5] = (short)f2bf(x1.y);
        ef[6] = (short)f2bf(x1.z); ef[7] = (short)f2bf(x1.w);
        #pragma unroll
        for (int hf = 0; hf < 2; ++hf)
          oacc[h][hf] = __builtin_amdgcn_mfma_f32_16x16x32_bf16(ef, vf[h][hf], oacc[h][hf], 0, 0, 0);
      }
    }
    // attn head-mean readback: 16 rows x 64 floats = full 256-B lines
    {
      const int ks = cq >> 1, ch = (cq & 1) * 16;
      const float* e0 = &Esh[wv][0][ks][rrow * 36 + ch];
      const float* e1 = &Esh[wv][1][ks][rrow * 36 + ch];
      float* ap = &attn[(size_t)(qt0 + rrow) * NN + kbase + cq * 16];
      #pragma unroll
      for (int j = 0; j < 4; ++j) {
        const float4 a = *(const float4*)(e0 + j * 4);
        const float4 b = *(const float4*)(e1 + j * 4);
        float4 m;
        m.x = 0.5f * (a.x + b.x); m.y = 0.5f * (a.y + b.y);
        m.z = 0.5f * (a.z + b.z); m.w = 0.5f * (a.w + b.w);
        *(float4*)(ap + j * 4) = m;
      }
    }
  }
  #pragma unroll
  for (int h = 0; h < 2; ++h)
    #pragma unroll
    for (int hf = 0; hf < 2; ++hf)
      #pragma unroll
      for (int r = 0; r < 4; ++r)
        atomicAdd(&Osh[(quad * 4 + r) * 64 + h * 32 + hf * 16 + ql], oacc[h][hf][r]);
  __syncthreads();
  for (int idx = tid; idx < 16 * 64; idx += 512)
    O[(size_t)qt0 * 64 + idx] = Osh[idx];
}

// ---------------- tail: h_attn=O@Wo+bo ; y1=relu([htkg|h_attn]@fc1+b) ; pred=y1@fc2+b ----
__global__ __launch_bounds__(256) void tail_k(const float* __restrict__ O,
    const float* __restrict__ htkg, const float* __restrict__ Wo, const float* __restrict__ bo,
    const float* __restrict__ fc1W, const float* __restrict__ fc1b,
    const float* __restrict__ fc2W, const float* __restrict__ fc2b,
    float* __restrict__ pred) {
  __shared__ float Ws[8192];
  __shared__ float T1[2048];
  __shared__ float T2[2048];
  const int tid = threadIdx.x;
  const int col = tid & 63, rg = tid >> 6;
  const int rowbase = blockIdx.x * 32;
  for (int i = tid; i < 2048; i += 256) T1[i] = O[(size_t)rowbase * 64 + i];
  for (int i = tid; i < 4096; i += 256) Ws[i] = Wo[i];
  const float rbo = bo[col], rf1b = fc1b[col], rf2 = fc2W[col], rf2b = fc2b[0];
  __syncthreads();
  float ha[8];
  #pragma unroll
  for (int r = 0; r < 8; ++r) {
    const int row = rg * 8 + r;
    float acc = rbo;
    for (int k = 0; k < 64; ++k) acc = fmaf(T1[row * 64 + k], Ws[k * 64 + col], acc);
    ha[r] = acc;
  }
  __syncthreads();
  #pragma unroll
  for (int r = 0; r < 8; ++r) T2[(rg * 8 + r) * 64 + col] = ha[r];
  for (int i = tid; i < 2048; i += 256) T1[i] = htkg[(size_t)rowbase * 64 + i];
  for (int i = tid; i < 8192; i += 256) Ws[i] = fc1W[i];
  __syncthreads();
  #pragma unroll
  for (int r = 0; r < 8; ++r) {
    const int row = rg * 8 + r;
    float acc = rf1b;
    for (int k = 0; k < 64; ++k) acc = fmaf(T1[row * 64 + k], Ws[k * 64 + col], acc);
    for (int k = 0; k < 64; ++k) acc = fmaf(T2[row * 64 + k], Ws[(64 + k) * 64 + col], acc);
    float y = fmaxf(acc, 0.f);
    float v = y * rf2;
    #pragma unroll
    for (int m = 32; m >= 1; m >>= 1) v += __shfl_xor(v, m);
    if (col == 0) pred[rowbase + row] = v + rf2b;
  }
}

extern "C" void kernel_launch(void* const* d_in, const int* in_sizes, int n_in,
                              void* d_out, int out_size, void* d_ws, size_t ws_size,
                              hipStream_t stream) {
  (void)in_sizes; (void)n_in; (void)out_size; (void)ws_size;
  const float* x       = (const float*)d_in[0];
  const int*   ei_t    = (const int*)d_in[1];
  const int*   ei_e    = (const int*)d_in[2];
  const float* gat1_W  = (const float*)d_in[3];
  const float* gat1_as = (const float*)d_in[4];
  const float* gat1_ad = (const float*)d_in[5];
  const float* gat1_b  = (const float*)d_in[6];
  const float* gat2_W  = (const float*)d_in[7];
  const float* gat2_as = (const float*)d_in[8];
  const float* gat2_ad = (const float*)d_in[9];
  const float* gat2_b  = (const float*)d_in[10];
  const float* gcn1_W  = (const float*)d_in[11];
  const float* gcn1_b  = (const float*)d_in[12];
  const float* gcn2_W  = (const float*)d_in[13];
  const float* gcn2_b  = (const float*)d_in[14];
  const float* Wq = (const float*)d_in[15]; const float* bq = (const float*)d_in[16];
  const float* Wk = (const float*)d_in[17]; const float* bk = (const float*)d_in[18];
  const float* Wv = (const float*)d_in[19]; const float* bv = (const float*)d_in[20];
  const float* Wo = (const float*)d_in[21]; const float* bo = (const float*)d_in[22];
  const float* fc1_W = (const float*)d_in[23]; const float* fc1_b = (const float*)d_in[24];
  const float* fc2_W = (const float*)d_in[25]; const float* fc2_b = (const float*)d_in[26];

  float* out  = (float*)d_out;
  float* attn = out + NN;   // [N, N] fp32, after pred[N]

  char* wsp = (char*)d_ws;
  size_t ofs = 0;
  auto take = [&](size_t bytes) -> char* {
    char* p = wsp + ofs;
    ofs = (ofs + bytes + 255) & ~(size_t)255;
    return p;
  };
  // ---- contiguous zero-init region first (single memset) ----
  int*   pos_t = (int*)take(NN * 4);
  int*   pos_e = (int*)take(NN * 4);
  float* a_s1  = (float*)take((size_t)NN * 2 * 4);
  float* a_d1  = (float*)take((size_t)NN * 2 * 4);
  float* a_s2  = (float*)take((size_t)NN * 4);
  float* a_d2  = (float*)take((size_t)NN * 4);
  const size_t zero_span = ofs;
  // ---- rest ----
  int* off_t = (int*)take((NN + 1) * 4);
  int* off_e = (int*)take((NN + 1) * 4);
  int* src_t = (int*)take((size_t)ET * 4);
  int* src_e = (int*)take((size_t)ET * 4);
  float* h1    = (float*)take((size_t)NN * 128 * 4);
  float* g1out = (float*)take((size_t)NN * 128 * 4);
  float* h2    = (float*)take((size_t)NN * 64 * 4);
  float* htkg  = (float*)take((size_t)NN * 64 * 4);
  float* hg1   = (float*)take((size_t)NN * 64 * 4);
  float* h2g   = (float*)take((size_t)NN * 64 * 4);
  float* hekg  = (float*)take((size_t)NN * 64 * 4);
  unsigned short* qb = (unsigned short*)take((size_t)NN * 64 * 2);
  unsigned short* kb = (unsigned short*)take((size_t)NN * 64 * 2);
  unsigned short* Vt = (unsigned short*)take((size_t)64 * NN * 2);
  float* Obuf  = (float*)take((size_t)NN * 64 * 4);

  hipMemsetAsync(wsp, 0, zero_span, stream);

  // CSR for both graphs
  edge_hist2_k<<<2 * ET / 256, 256, 0, stream>>>(ei_t, ei_e, pos_t, pos_e);
  scan2_k<<<2, 1024, 0, stream>>>(pos_t, off_t, pos_e, off_e);
  edge_scatter2_k<<<2 * ET / 256, 256, 0, stream>>>(ei_t, ei_e, pos_t, pos_e, src_t, src_e);

  // x projections for both branches + gat1 att_sd epilogue
  mm_x_k<<<dim3(128, 6), 256, 0, stream>>>(x, gat1_W, gcn1_W, gat1_as, gat1_ad,
                                           h1, hg1, a_s1, a_d1);
  // merged gat1-agg + gcn1-agg+gemv
  agg1_k<<<NN + NN / 2, 128, 0, stream>>>(h1, a_s1, a_d1, off_t, src_t, gat1_b, g1out,
                                          hg1, off_e, src_e, gcn1_b, gcn2_W, h2g);
  // merged mm_gat2 + gcn_agg2
  mm2_k<<<256 + NN / 4, 256, 0, stream>>>(g1out, gat2_W, gat2_as, gat2_ad, h2, a_s2, a_d2,
                                          h2g, off_e, src_e, gcn2_b, hekg);
  // gat layer-2 aggregation
  gat_agg_k<1, 64><<<NN, 64, 0, stream>>>(h2, a_s2, a_d2, off_t, src_t, gat2_b, htkg, 64);

  // qkv projections + V transpose
  mm_qkv_k<<<dim3(128, 6), 256, 0, stream>>>(htkg, hekg, Wq, bq, Wk, bk, Wv, bv, qb, kb, Vt);

  // fused attention: 8 waves/block, 64-key iterations (full-line attn writes)
  att_fused<<<512, 512, 0, stream>>>(qb, kb, Vt, attn, Obuf);

  // fused epilogue: Wo + fc1 + fc2
  tail_k<<<256, 256, 0, stream>>>(Obuf, htkg, Wo, bo, fc1_W, fc1_b, fc2_W, fc2_b, out);
}

// Round 4
// 580.660 us; speedup vs baseline: 1.2937x; 1.1910x over previous
//
#include <hip/hip_runtime.h>
#include <cstdint>
#include <cstddef>

#define NN 8192
#define EE 262144
#define ET 270336   // EE + NN self loops

using short8  = __attribute__((ext_vector_type(8))) short;
using floatx4 = __attribute__((ext_vector_type(4))) float;

__device__ __forceinline__ unsigned short f2bf(float f) {
  unsigned int u = __float_as_uint(f);
  u += 0x7fffu + ((u >> 16) & 1u);          // RNE
  return (unsigned short)(u >> 16);
}

// ---------------- CSR build, both graphs in one launch ----------------
__global__ void edge_hist2_k(const int* __restrict__ ei_t, const int* __restrict__ ei_e,
                             int* __restrict__ cnt_t, int* __restrict__ cnt_e) {
  int idx = blockIdx.x * 256 + threadIdx.x;
  int g = idx >= ET;                        // block-uniform (ET % 256 == 0)
  int e = g ? idx - ET : idx;
  const int* ei = g ? ei_e : ei_t;
  int* cnt = g ? cnt_e : cnt_t;
  int d = (e < EE) ? ei[EE + e] : (e - EE);
  atomicAdd(&cnt[d], 1);
}

__global__ void scan2_k(int* cnt_t, int* off_t, int* cnt_e, int* off_e) {
  int* cnt = blockIdx.x ? cnt_e : cnt_t;    // pos aliases cnt (overwritten)
  int* off = blockIdx.x ? off_e : off_t;
  __shared__ int s[1024];
  int t = threadIdx.x;
  int v[8]; int base = t * 8; int sum = 0;
  #pragma unroll
  for (int j = 0; j < 8; ++j) { v[j] = cnt[base + j]; sum += v[j]; }
  s[t] = sum; __syncthreads();
  for (int o = 1; o < 1024; o <<= 1) {
    int x = (t >= o) ? s[t - o] : 0;
    __syncthreads();
    s[t] += x;
    __syncthreads();
  }
  int excl = s[t] - sum;
  #pragma unroll
  for (int j = 0; j < 8; ++j) { off[base + j] = excl; cnt[base + j] = excl; excl += v[j]; }
  if (t == 1023) off[NN] = excl;
}

__global__ void edge_scatter2_k(const int* __restrict__ ei_t, const int* __restrict__ ei_e,
                                int* __restrict__ pos_t, int* __restrict__ pos_e,
                                int* __restrict__ srcs_t, int* __restrict__ srcs_e) {
  int idx = blockIdx.x * 256 + threadIdx.x;
  int g = idx >= ET;
  int e = g ? idx - ET : idx;
  const int* ei = g ? ei_e : ei_t;
  int* pos = g ? pos_e : pos_t;
  int* srcs = g ? srcs_e : srcs_t;
  int sv, d;
  if (e < EE) { sv = ei[e]; d = ei[EE + e]; } else { sv = d = e - EE; }
  int p = atomicAdd(&pos[d], 1);
  srcs[p] = sv;
}

// ---------------- shared GEMM inner loop ----------------
__device__ __forceinline__ void gemm_core(const float* __restrict__ A, int lda, int K,
                                          const float* __restrict__ Bs, int row0, int col,
                                          float acc[8]) {
  #pragma unroll
  for (int r = 0; r < 8; ++r) acc[r] = 0.f;
  for (int k = 0; k < K; k += 4) {
    float b0 = Bs[(k + 0) * 32 + col], b1 = Bs[(k + 1) * 32 + col];
    float b2 = Bs[(k + 2) * 32 + col], b3 = Bs[(k + 3) * 32 + col];
    #pragma unroll
    for (int r = 0; r < 8; ++r) {
      const float4 a4 = *(const float4*)(A + (size_t)(row0 + r) * lda + k);
      acc[r] = fmaf(a4.x, b0, acc[r]);
      acc[r] = fmaf(a4.y, b1, acc[r]);
      acc[r] = fmaf(a4.z, b2, acc[r]);
      acc[r] = fmaf(a4.w, b3, acc[r]);
    }
  }
}

// ---------------- mm_x: h1 = x@gat1_W (+att_sd epilogue), hg1 = x@gcn1_W ----------------
__global__ __launch_bounds__(256) void mm_x_k(const float* __restrict__ x,
    const float* __restrict__ Wgat, const float* __restrict__ Wgcn,
    const float* __restrict__ as_w, const float* __restrict__ ad_w,
    float* __restrict__ h1, float* __restrict__ hg1,
    float* __restrict__ a_s1, float* __restrict__ a_d1) {
  __shared__ float Bs[256 * 32];
  const int tid = threadIdx.x, by = blockIdx.y;
  const bool gat = by < 4;
  const int NC = gat ? 128 : 64;
  const int c0 = gat ? by * 32 : (by - 4) * 32;
  const float* B = gat ? Wgat : Wgcn;
  for (int idx = tid; idx < 256 * 32; idx += 256)
    Bs[idx] = B[(idx >> 5) * NC + c0 + (idx & 31)];
  __syncthreads();
  const int row0 = blockIdx.x * 64 + (tid >> 5) * 8;
  const int col = tid & 31;
  float acc[8];
  gemm_core(x, 256, 256, Bs, row0, col, acc);
  if (gat) {
    #pragma unroll
    for (int r = 0; r < 8; ++r) h1[(size_t)(row0 + r) * 128 + c0 + col] = acc[r];
    const int head = c0 >> 6;
    const float asw = as_w[head * 64 + (c0 & 63) + col];
    const float adw = ad_w[head * 64 + (c0 & 63) + col];
    float ps[8], pd[8];
    #pragma unroll
    for (int r = 0; r < 8; ++r) { ps[r] = acc[r] * asw; pd[r] = acc[r] * adw; }
    #pragma unroll
    for (int m = 16; m >= 1; m >>= 1)
      #pragma unroll
      for (int r = 0; r < 8; ++r) { ps[r] += __shfl_xor(ps[r], m); pd[r] += __shfl_xor(pd[r], m); }
    if (col == 0) {
      #pragma unroll
      for (int r = 0; r < 8; ++r) {
        atomicAdd(&a_s1[(row0 + r) * 2 + head], ps[r]);
        atomicAdd(&a_d1[(row0 + r) * 2 + head], pd[r]);
      }
    }
  } else {
    #pragma unroll
    for (int r = 0; r < 8; ++r) hg1[(size_t)(row0 + r) * 64 + c0 + col] = acc[r];
  }
}

// ---------------- GAT aggregation ----------------
template<int H, int C>
__device__ __forceinline__ void gat_agg_body(const float* __restrict__ h,
    const float* __restrict__ a_s, const float* __restrict__ a_d,
    const int* __restrict__ off, const int* __restrict__ srcs,
    const float* __restrict__ bias, float* __restrict__ out, int ldout, int b) {
  constexpr int HC = H * C;
  const int tid = threadIdx.x;
  const int hd = tid / C;
  const int r0 = off[b], r1 = off[b + 1];
  __shared__ int s_src[HC];
  __shared__ float s_w[HC][H];
  float ad[H];
  #pragma unroll
  for (int hh = 0; hh < H; ++hh) ad[hh] = a_d[b * H + hh];
  float acc = 0.f, den = 0.f;
  for (int base = r0; base < r1; base += HC) {
    __syncthreads();
    int e = base + tid;
    if (e < r1) {
      int sv = srcs[e];
      s_src[tid] = sv;
      #pragma unroll
      for (int hh = 0; hh < H; ++hh) {
        float xv = a_s[sv * H + hh] + ad[hh];
        xv = xv > 0.f ? xv : 0.2f * xv;     // leaky_relu 0.2
        s_w[tid][hh] = __expf(xv);
      }
    }
    __syncthreads();
    int cnt = min(HC, r1 - base);
    for (int j = 0; j < cnt; ++j) {
      float wv = s_w[j][hd];
      den += wv;
      acc = fmaf(wv, h[(size_t)s_src[j] * HC + tid], acc);
    }
  }
  float o = acc / den + bias[tid];
  out[(size_t)b * ldout + tid] = o > 0.f ? o : (__expf(o) - 1.f);  // elu
}

template<int H, int C>
__global__ void gat_agg_k(const float* __restrict__ h, const float* __restrict__ a_s,
                          const float* __restrict__ a_d, const int* __restrict__ off,
                          const int* __restrict__ srcs, const float* __restrict__ bias,
                          float* __restrict__ out, int ldout) {
  gat_agg_body<H, C>(h, a_s, a_d, off, srcs, bias, out, ldout, blockIdx.x);
}

// ---------------- merged: gat1 aggregation (blocks 0..NN) + gcn1 agg+gemv (2 nodes/blk) ----
__global__ __launch_bounds__(128) void agg1_k(
    const float* __restrict__ h1, const float* __restrict__ a_s1, const float* __restrict__ a_d1,
    const int* __restrict__ off_t, const int* __restrict__ src_t,
    const float* __restrict__ gat1_b, float* __restrict__ g1out,
    const float* __restrict__ hg1, const int* __restrict__ off_e, const int* __restrict__ src_e,
    const float* __restrict__ gcn1_b, const float* __restrict__ gcn2_W, float* __restrict__ h2g) {
  const int tid = threadIdx.x;
  if (blockIdx.x < NN) {
    gat_agg_body<2, 64>(h1, a_s1, a_d1, off_t, src_t, gat1_b, g1out, 128, blockIdx.x);
  } else {
    const int nb = (blockIdx.x - NN) * 2;
    const int sub = tid >> 6, t = tid & 63;
    const int node = nb + sub;
    __shared__ int s_src2[2][64];
    __shared__ float s_nrm2[2][64];
    __shared__ float s_row2[2][64];
    const int r0 = off_e[node], r1 = off_e[node + 1];
    const int cA = off_e[nb + 1] - off_e[nb];
    const int cB = off_e[nb + 2] - off_e[nb + 1];
    const int trips = (max(cA, cB) + 63) >> 6;
    float dinv_b = rsqrtf((float)max(r1 - r0, 1));
    float acc = 0.f;
    for (int it = 0; it < trips; ++it) {
      __syncthreads();
      int e = r0 + it * 64 + t;
      if (e < r1) {
        int sv = src_e[e];
        s_src2[sub][t] = sv;
        int ds = off_e[sv + 1] - off_e[sv];
        s_nrm2[sub][t] = dinv_b * rsqrtf((float)max(ds, 1));
      }
      __syncthreads();
      int cnt = min(64, r1 - (r0 + it * 64));
      for (int j = 0; j < cnt; ++j)
        acc = fmaf(s_nrm2[sub][j], hg1[(size_t)s_src2[sub][j] * 64 + t], acc);
    }
    s_row2[sub][t] = fmaxf(acc + gcn1_b[t], 0.f);
    __syncthreads();
    float acc2 = 0.f;
    for (int k = 0; k < 64; ++k)
      acc2 = fmaf(s_row2[sub][k], gcn2_W[k * 64 + t], acc2);
    h2g[(size_t)node * 64 + t] = acc2;
  }
}

// ---------------- merged: mm_gat2 (blocks 0..256) + gcn_agg2 (4 nodes/blk) ----------------
__global__ __launch_bounds__(256) void mm2_k(
    const float* __restrict__ g1out, const float* __restrict__ gat2_W,
    const float* __restrict__ gat2_as, const float* __restrict__ gat2_ad,
    float* __restrict__ h2, float* __restrict__ a_s2, float* __restrict__ a_d2,
    const float* __restrict__ h2g, const int* __restrict__ off_e, const int* __restrict__ src_e,
    const float* __restrict__ gcn2_b, float* __restrict__ hekg) {
  const int tid = threadIdx.x;
  if (blockIdx.x < 256) {
    __shared__ float Bs[128 * 32];
    const int bx = blockIdx.x & 127;
    const int c0 = (blockIdx.x >> 7) * 32;
    for (int idx = tid; idx < 128 * 32; idx += 256)
      Bs[idx] = gat2_W[(idx >> 5) * 64 + c0 + (idx & 31)];
    __syncthreads();
    const int row0 = bx * 64 + (tid >> 5) * 8;
    const int col = tid & 31;
    float acc[8];
    gemm_core(g1out, 128, 128, Bs, row0, col, acc);
    const float asw = gat2_as[c0 + col];
    const float adw = gat2_ad[c0 + col];
    float ps[8], pd[8];
    #pragma unroll
    for (int r = 0; r < 8; ++r) {
      h2[(size_t)(row0 + r) * 64 + c0 + col] = acc[r];
      ps[r] = acc[r] * asw; pd[r] = acc[r] * adw;
    }
    #pragma unroll
    for (int m = 16; m >= 1; m >>= 1)
      #pragma unroll
      for (int r = 0; r < 8; ++r) { ps[r] += __shfl_xor(ps[r], m); pd[r] += __shfl_xor(pd[r], m); }
    if (col == 0) {
      #pragma unroll
      for (int r = 0; r < 8; ++r) {
        atomicAdd(&a_s2[row0 + r], ps[r]);
        atomicAdd(&a_d2[row0 + r], pd[r]);
      }
    }
  } else {
    const int nb = (blockIdx.x - 256) * 4;
    const int sub = tid >> 6, t = tid & 63;
    const int node = nb + sub;
    __shared__ int s_src4[4][64];
    __shared__ float s_nrm4[4][64];
    const int r0 = off_e[node], r1 = off_e[node + 1];
    int cmax = 0;
    #pragma unroll
    for (int i = 0; i < 4; ++i) cmax = max(cmax, off_e[nb + i + 1] - off_e[nb + i]);
    const int trips = (cmax + 63) >> 6;
    float dinv_b = rsqrtf((float)max(r1 - r0, 1));
    float acc = 0.f;
    for (int it = 0; it < trips; ++it) {
      __syncthreads();
      int e = r0 + it * 64 + t;
      if (e < r1) {
        int sv = src_e[e];
        s_src4[sub][t] = sv;
        int ds = off_e[sv + 1] - off_e[sv];
        s_nrm4[sub][t] = dinv_b * rsqrtf((float)max(ds, 1));
      }
      __syncthreads();
      int cnt = min(64, r1 - (r0 + it * 64));
      for (int j = 0; j < cnt; ++j)
        acc = fmaf(s_nrm4[sub][j], h2g[(size_t)s_src4[sub][j] * 64 + t], acc);
    }
    hekg[(size_t)node * 64 + t] = fmaxf(acc + gcn2_b[t], 0.f);
  }
}

// ---------------- qkv projections (+V transpose) ----------------
__global__ __launch_bounds__(256) void mm_qkv_k(const float* __restrict__ htkg,
    const float* __restrict__ hekg,
    const float* __restrict__ Wq, const float* __restrict__ bq,
    const float* __restrict__ Wk, const float* __restrict__ bk,
    const float* __restrict__ Wv, const float* __restrict__ bv,
    unsigned short* __restrict__ qb, unsigned short* __restrict__ kb,
    unsigned short* __restrict__ Vt) {
  __shared__ float Bs[64 * 32];
  __shared__ float Ts[32][65];
  const int tid = threadIdx.x, by = blockIdx.y;
  const int kind = by >> 1;
  const int c0 = (by & 1) * 32;
  const float* A = (kind == 0) ? htkg : hekg;
  const float* B = (kind == 0) ? Wq : (kind == 1) ? Wk : Wv;
  const float* bias = (kind == 0) ? bq : (kind == 1) ? bk : bv;
  for (int idx = tid; idx < 64 * 32; idx += 256)
    Bs[idx] = B[(idx >> 5) * 64 + c0 + (idx & 31)];
  __syncthreads();
  const int row0 = blockIdx.x * 64 + (tid >> 5) * 8;
  const int col = tid & 31;
  float acc[8];
  gemm_core(A, 64, 64, Bs, row0, col, acc);
  const float bb = bias[c0 + col];
  if (kind == 0) {
    const float SCL = 0.17677669529663687f * 1.4426950408889634f;  // 1/sqrt(32) * log2(e)
    #pragma unroll
    for (int r = 0; r < 8; ++r)
      qb[(size_t)(row0 + r) * 64 + c0 + col] = f2bf((acc[r] + bb) * SCL);
  } else if (kind == 1) {
    #pragma unroll
    for (int r = 0; r < 8; ++r)
      kb[(size_t)(row0 + r) * 64 + c0 + col] = f2bf(acc[r] + bb);
  } else {
    const int rl = (tid >> 5) * 8;
    #pragma unroll
    for (int r = 0; r < 8; ++r) Ts[col][rl + r] = acc[r] + bb;
    __syncthreads();
    const int c = tid >> 3, rr = (tid & 7) * 8;
    short8 pk;
    #pragma unroll
    for (int j = 0; j < 8; ++j) pk[j] = (short)f2bf(Ts[c][rr + j]);
    *(short8*)(Vt + (size_t)(c0 + c) * NN + blockIdx.x * 64 + rr) = pk;
  }
}

// ---------------- attention pass 1: softmax denominators ----------------
// grid (64,8), 256 thr (4 waves). Block = 128 q-rows x 1024-key split.
// K tiles (64 keys, 8KB) staged to LDS (XOR-swizzled, reg-staged, double-buffered),
// shared by all waves -> global K traffic cut 8x vs per-wave strip loads.
__global__ __launch_bounds__(256) void att_lsum_k(
    const unsigned short* __restrict__ qb, const unsigned short* __restrict__ kb,
    float* __restrict__ lsum) {
  __shared__ __align__(16) short Kbuf[2][64 * 64];
  const int tid = threadIdx.x;
  const int lane = tid & 63, wv = tid >> 6;
  const int ql = lane & 15, quad = lane >> 4;
  const int q0 = blockIdx.x * 128 + wv * 32;
  const int k0 = blockIdx.y * 1024;
  const floatx4 zf = {0.f, 0.f, 0.f, 0.f};

  short8 qf[2][2];
  #pragma unroll
  for (int qt = 0; qt < 2; ++qt)
    #pragma unroll
    for (int h = 0; h < 2; ++h)
      qf[qt][h] = *(const short8*)(qb + (size_t)(q0 + qt * 16 + ql) * 64 + h * 32 + quad * 8);

  const int sr = tid >> 3, sc = tid & 7;     // staging: rows sr, sr+32; colblk sc
  const int swc0 = (sc ^ (sr & 7)) * 8;
  const int swc1 = (sc ^ ((sr + 32) & 7)) * 8;
  short8 kr0, kr1;

  float lacc[2][2][4];
  #pragma unroll
  for (int qt = 0; qt < 2; ++qt)
    #pragma unroll
    for (int h = 0; h < 2; ++h)
      #pragma unroll
      for (int r = 0; r < 4; ++r) lacc[qt][h][r] = 0.f;

  // prologue: stage tile 0
  {
    const unsigned short* src = kb + (size_t)k0 * 64;
    kr0 = *(const short8*)(src + sr * 64 + sc * 8);
    kr1 = *(const short8*)(src + (sr + 32) * 64 + sc * 8);
    *(short8*)&Kbuf[0][sr * 64 + swc0] = kr0;
    *(short8*)&Kbuf[0][(sr + 32) * 64 + swc1] = kr1;
  }
  __syncthreads();

  for (int t = 0; t < 16; ++t) {
    if (t < 15) {
      const unsigned short* src = kb + (size_t)(k0 + (t + 1) * 64) * 64;
      kr0 = *(const short8*)(src + sr * 64 + sc * 8);
      kr1 = *(const short8*)(src + (sr + 32) * 64 + sc * 8);
    }
    const short* Kc = Kbuf[t & 1];
    #pragma unroll
    for (int kt = 0; kt < 4; ++kt) {
      const int row = kt * 16 + ql;
      short8 kf[2];
      #pragma unroll
      for (int h = 0; h < 2; ++h)
        kf[h] = *(const short8*)&Kc[row * 64 + ((h * 4 + quad) ^ (row & 7)) * 8];
      #pragma unroll
      for (int qt = 0; qt < 2; ++qt)
        #pragma unroll
        for (int h = 0; h < 2; ++h) {
          floatx4 s = __builtin_amdgcn_mfma_f32_16x16x32_bf16(qf[qt][h], kf[h], zf, 0, 0, 0);
          #pragma unroll
          for (int r = 0; r < 4; ++r) lacc[qt][h][r] += __builtin_amdgcn_exp2f(s[r]);
        }
    }
    if (t < 15) {
      *(short8*)&Kbuf[(t + 1) & 1][sr * 64 + swc0] = kr0;
      *(short8*)&Kbuf[(t + 1) & 1][(sr + 32) * 64 + swc1] = kr1;
    }
    __syncthreads();
  }

  #pragma unroll
  for (int o = 8; o >= 1; o >>= 1)
    #pragma unroll
    for (int qt = 0; qt < 2; ++qt)
      #pragma unroll
      for (int h = 0; h < 2; ++h)
        #pragma unroll
        for (int r = 0; r < 4; ++r)
          lacc[qt][h][r] += __shfl_xor(lacc[qt][h][r], o, 16);
  if (ql == 0) {
    #pragma unroll
    for (int qt = 0; qt < 2; ++qt)
      #pragma unroll
      for (int h = 0; h < 2; ++h)
        #pragma unroll
        for (int r = 0; r < 4; ++r)
          atomicAdd(&lsum[(q0 + qt * 16 + quad * 4 + r) * 2 + h], lacc[qt][h][r]);
  }
}

// ---------------- attention pass 2: P/attn/PV with LDS-shared K/V tiles ----------------
// grid (64,8), 512 thr (8 waves). Block = 128 q-rows x 1024-key split; wave = 16 q-rows.
// K and V 64-key tiles staged once per block (double-buffered, XOR-swizzled).
// attn head-mean written straight from registers (both heads live in the same lane);
// each 128-B line completes within one sub-step -> clean write merging.
// O partials accumulated via global f32 atomics into zeroed Obuf.
__global__ __launch_bounds__(512, 4) void att_pv_k(
    const unsigned short* __restrict__ qb, const unsigned short* __restrict__ kb,
    const unsigned short* __restrict__ Vt, const float* __restrict__ lsum,
    float* __restrict__ attn, float* __restrict__ O) {
  __shared__ __align__(16) short Kbuf[2][64 * 64];
  __shared__ __align__(16) short Vbuf[2][64 * 64];
  __shared__ __align__(16) float Esh[8][2][16 * 36];
  const int tid = threadIdx.x;
  const int lane = tid & 63, wv = tid >> 6;
  const int ql = lane & 15, quad = lane >> 4;
  const int q0 = blockIdx.x * 128 + wv * 16;
  const int k0 = blockIdx.y * 1024;
  const floatx4 zf = {0.f, 0.f, 0.f, 0.f};

  short8 qf[2];
  #pragma unroll
  for (int h = 0; h < 2; ++h)
    qf[h] = *(const short8*)(qb + (size_t)(q0 + ql) * 64 + h * 32 + quad * 8);

  float invl[2][4];
  #pragma unroll
  for (int h = 0; h < 2; ++h)
    #pragma unroll
    for (int r = 0; r < 4; ++r)
      invl[h][r] = 1.0f / lsum[(q0 + quad * 4 + r) * 2 + h];

  const int sr = tid >> 3, sc = tid & 7;   // staging row (0..63), colblk (0..7)
  const int swc = (sc ^ (sr & 7)) * 8;
  short8 krg, vrg;

  floatx4 oacc[2][2];
  #pragma unroll
  for (int h = 0; h < 2; ++h)
    #pragma unroll
    for (int hf = 0; hf < 2; ++hf) oacc[h][hf] = zf;

  // prologue: stage tile 0
  {
    krg = *(const short8*)(kb + (size_t)(k0 + sr) * 64 + sc * 8);
    vrg = *(const short8*)(Vt + (size_t)sr * NN + k0 + sc * 8);
    *(short8*)&Kbuf[0][sr * 64 + swc] = krg;
    *(short8*)&Vbuf[0][sr * 64 + swc] = vrg;
  }
  __syncthreads();

  for (int t = 0; t < 16; ++t) {
    if (t < 15) {
      krg = *(const short8*)(kb + (size_t)(k0 + (t + 1) * 64 + sr) * 64 + sc * 8);
      vrg = *(const short8*)(Vt + (size_t)sr * NN + k0 + (t + 1) * 64 + sc * 8);
    }
    const short* Kc = Kbuf[t & 1];
    const short* Vc = Vbuf[t & 1];
    #pragma unroll
    for (int ks = 0; ks < 2; ++ks) {
      short8 kf[2][2], vf[2][2];
      #pragma unroll
      for (int kt = 0; kt < 2; ++kt) {
        const int row = ks * 32 + kt * 16 + ql;
        #pragma unroll
        for (int h = 0; h < 2; ++h)
          kf[kt][h] = *(const short8*)&Kc[row * 64 + ((h * 4 + quad) ^ (row & 7)) * 8];
      }
      #pragma unroll
      for (int h = 0; h < 2; ++h)
        #pragma unroll
        for (int hf = 0; hf < 2; ++hf) {
          const int d = h * 32 + hf * 16 + ql;
          vf[h][hf] = *(const short8*)&Vc[d * 64 + ((ks * 4 + quad) ^ (d & 7)) * 8];
        }

      floatx4 p[2][2];  // [head][kt]
      #pragma unroll
      for (int h = 0; h < 2; ++h)
        #pragma unroll
        for (int kt = 0; kt < 2; ++kt) {
          floatx4 s = __builtin_amdgcn_mfma_f32_16x16x32_bf16(qf[h], kf[kt][h], zf, 0, 0, 0);
          #pragma unroll
          for (int r = 0; r < 4; ++r)
            p[h][kt][r] = __builtin_amdgcn_exp2f(s[r]) * invl[h][r];
        }
      // attn head-mean straight from registers (line completes within sub-step)
      #pragma unroll
      for (int kt = 0; kt < 2; ++kt)
        #pragma unroll
        for (int r = 0; r < 4; ++r)
          attn[(size_t)(q0 + quad * 4 + r) * NN + k0 + t * 64 + ks * 32 + kt * 16 + ql] =
              0.5f * (p[0][kt][r] + p[1][kt][r]);
      // C-layout -> LDS -> A-layout, PV mfma
      #pragma unroll
      for (int h = 0; h < 2; ++h)
        #pragma unroll
        for (int kt = 0; kt < 2; ++kt)
          #pragma unroll
          for (int r = 0; r < 4; ++r)
            Esh[wv][h][(quad * 4 + r) * 36 + kt * 16 + ql] = p[h][kt][r];
      #pragma unroll
      for (int h = 0; h < 2; ++h) {
        const float* ep = &Esh[wv][h][ql * 36 + quad * 8];
        float4 x0 = *(const float4*)ep;
        float4 x1 = *(const float4*)(ep + 4);
        short8 ef;
        ef[0] = (short)f2bf(x0.x); ef[1] = (short)f2bf(x0.y);
        ef[2] = (short)f2bf(x0.z); ef[3] = (short)f2bf(x0.w);
        ef[4] = (short)f2bf(x1.x); ef[5] = (short)f2bf(x1.y);
        ef[6] = (short)f2bf(x1.z); ef[7] = (short)f2bf(x1.w);
        #pragma unroll
        for (int hf = 0; hf < 2; ++hf)
          oacc[h][hf] = __builtin_amdgcn_mfma_f32_16x16x32_bf16(ef, vf[h][hf], oacc[h][hf], 0, 0, 0);
      }
    }
    if (t < 15) {
      *(short8*)&Kbuf[(t + 1) & 1][sr * 64 + swc] = krg;
      *(short8*)&Vbuf[(t + 1) & 1][sr * 64 + swc] = vrg;
    }
    __syncthreads();
  }

  #pragma unroll
  for (int h = 0; h < 2; ++h)
    #pragma unroll
    for (int hf = 0; hf < 2; ++hf)
      #pragma unroll
      for (int r = 0; r < 4; ++r)
        atomicAdd(&O[(size_t)(q0 + quad * 4 + r) * 64 + h * 32 + hf * 16 + ql], oacc[h][hf][r]);
}

// ---------------- tail: h_attn=O@Wo+bo ; y1=relu([htkg|h_attn]@fc1+b) ; pred=y1@fc2+b ----
__global__ __launch_bounds__(256) void tail_k(const float* __restrict__ O,
    const float* __restrict__ htkg, const float* __restrict__ Wo, const float* __restrict__ bo,
    const float* __restrict__ fc1W, const float* __restrict__ fc1b,
    const float* __restrict__ fc2W, const float* __restrict__ fc2b,
    float* __restrict__ pred) {
  __shared__ float Ws[8192];
  __shared__ float T1[2048];
  __shared__ float T2[2048];
  const int tid = threadIdx.x;
  const int col = tid & 63, rg = tid >> 6;
  const int rowbase = blockIdx.x * 32;
  for (int i = tid; i < 2048; i += 256) T1[i] = O[(size_t)rowbase * 64 + i];
  for (int i = tid; i < 4096; i += 256) Ws[i] = Wo[i];
  const float rbo = bo[col], rf1b = fc1b[col], rf2 = fc2W[col], rf2b = fc2b[0];
  __syncthreads();
  float ha[8];
  #pragma unroll
  for (int r = 0; r < 8; ++r) {
    const int row = rg * 8 + r;
    float acc = rbo;
    for (int k = 0; k < 64; ++k) acc = fmaf(T1[row * 64 + k], Ws[k * 64 + col], acc);
    ha[r] = acc;
  }
  __syncthreads();
  #pragma unroll
  for (int r = 0; r < 8; ++r) T2[(rg * 8 + r) * 64 + col] = ha[r];
  for (int i = tid; i < 2048; i += 256) T1[i] = htkg[(size_t)rowbase * 64 + i];
  for (int i = tid; i < 8192; i += 256) Ws[i] = fc1W[i];
  __syncthreads();
  #pragma unroll
  for (int r = 0; r < 8; ++r) {
    const int row = rg * 8 + r;
    float acc = rf1b;
    for (int k = 0; k < 64; ++k) acc = fmaf(T1[row * 64 + k], Ws[k * 64 + col], acc);
    for (int k = 0; k < 64; ++k) acc = fmaf(T2[row * 64 + k], Ws[(64 + k) * 64 + col], acc);
    float y = fmaxf(acc, 0.f);
    float v = y * rf2;
    #pragma unroll
    for (int m = 32; m >= 1; m >>= 1) v += __shfl_xor(v, m);
    if (col == 0) pred[rowbase + row] = v + rf2b;
  }
}

extern "C" void kernel_launch(void* const* d_in, const int* in_sizes, int n_in,
                              void* d_out, int out_size, void* d_ws, size_t ws_size,
                              hipStream_t stream) {
  (void)in_sizes; (void)n_in; (void)out_size; (void)ws_size;
  const float* x       = (const float*)d_in[0];
  const int*   ei_t    = (const int*)d_in[1];
  const int*   ei_e    = (const int*)d_in[2];
  const float* gat1_W  = (const float*)d_in[3];
  const float* gat1_as = (const float*)d_in[4];
  const float* gat1_ad = (const float*)d_in[5];
  const float* gat1_b  = (const float*)d_in[6];
  const float* gat2_W  = (const float*)d_in[7];
  const float* gat2_as = (const float*)d_in[8];
  const float* gat2_ad = (const float*)d_in[9];
  const float* gat2_b  = (const float*)d_in[10];
  const float* gcn1_W  = (const float*)d_in[11];
  const float* gcn1_b  = (const float*)d_in[12];
  const float* gcn2_W  = (const float*)d_in[13];
  const float* gcn2_b  = (const float*)d_in[14];
  const float* Wq = (const float*)d_in[15]; const float* bq = (const float*)d_in[16];
  const float* Wk = (const float*)d_in[17]; const float* bk = (const float*)d_in[18];
  const float* Wv = (const float*)d_in[19]; const float* bv = (const float*)d_in[20];
  const float* Wo = (const float*)d_in[21]; const float* bo = (const float*)d_in[22];
  const float* fc1_W = (const float*)d_in[23]; const float* fc1_b = (const float*)d_in[24];
  const float* fc2_W = (const float*)d_in[25]; const float* fc2_b = (const float*)d_in[26];

  float* out  = (float*)d_out;
  float* attn = out + NN;   // [N, N] fp32, after pred[N]

  char* wsp = (char*)d_ws;
  size_t ofs = 0;
  auto take = [&](size_t bytes) -> char* {
    char* p = wsp + ofs;
    ofs = (ofs + bytes + 255) & ~(size_t)255;
    return p;
  };
  // ---- contiguous zero-init region first (single memset) ----
  int*   pos_t = (int*)take(NN * 4);
  int*   pos_e = (int*)take(NN * 4);
  float* a_s1  = (float*)take((size_t)NN * 2 * 4);
  float* a_d1  = (float*)take((size_t)NN * 2 * 4);
  float* a_s2  = (float*)take((size_t)NN * 4);
  float* a_d2  = (float*)take((size_t)NN * 4);
  float* a_l   = (float*)take((size_t)NN * 2 * 4);
  float* Obuf  = (float*)take((size_t)NN * 64 * 4);
  const size_t zero_span = ofs;
  // ---- rest ----
  int* off_t = (int*)take((NN + 1) * 4);
  int* off_e = (int*)take((NN + 1) * 4);
  int* src_t = (int*)take((size_t)ET * 4);
  int* src_e = (int*)take((size_t)ET * 4);
  float* h1    = (float*)take((size_t)NN * 128 * 4);
  float* g1out = (float*)take((size_t)NN * 128 * 4);
  float* h2    = (float*)take((size_t)NN * 64 * 4);
  float* htkg  = (float*)take((size_t)NN * 64 * 4);
  float* hg1   = (float*)take((size_t)NN * 64 * 4);
  float* h2g   = (float*)take((size_t)NN * 64 * 4);
  float* hekg  = (float*)take((size_t)NN * 64 * 4);
  unsigned short* qb = (unsigned short*)take((size_t)NN * 64 * 2);
  unsigned short* kb = (unsigned short*)take((size_t)NN * 64 * 2);
  unsigned short* Vt = (unsigned short*)take((size_t)64 * NN * 2);

  hipMemsetAsync(wsp, 0, zero_span, stream);

  // CSR for both graphs
  edge_hist2_k<<<2 * ET / 256, 256, 0, stream>>>(ei_t, ei_e, pos_t, pos_e);
  scan2_k<<<2, 1024, 0, stream>>>(pos_t, off_t, pos_e, off_e);
  edge_scatter2_k<<<2 * ET / 256, 256, 0, stream>>>(ei_t, ei_e, pos_t, pos_e, src_t, src_e);

  // x projections for both branches + gat1 att_sd epilogue
  mm_x_k<<<dim3(128, 6), 256, 0, stream>>>(x, gat1_W, gcn1_W, gat1_as, gat1_ad,
                                           h1, hg1, a_s1, a_d1);
  // merged gat1-agg + gcn1-agg+gemv
  agg1_k<<<NN + NN / 2, 128, 0, stream>>>(h1, a_s1, a_d1, off_t, src_t, gat1_b, g1out,
                                          hg1, off_e, src_e, gcn1_b, gcn2_W, h2g);
  // merged mm_gat2 + gcn_agg2
  mm2_k<<<256 + NN / 4, 256, 0, stream>>>(g1out, gat2_W, gat2_as, gat2_ad, h2, a_s2, a_d2,
                                          h2g, off_e, src_e, gcn2_b, hekg);
  // gat layer-2 aggregation
  gat_agg_k<1, 64><<<NN, 64, 0, stream>>>(h2, a_s2, a_d2, off_t, src_t, gat2_b, htkg, 64);

  // qkv projections + V transpose
  mm_qkv_k<<<dim3(128, 6), 256, 0, stream>>>(htkg, hekg, Wq, bq, Wk, bk, Wv, bv, qb, kb, Vt);

  // attention: q-block 128 x k-split 8, LDS-shared K/V tiles
  att_lsum_k<<<dim3(64, 8), 256, 0, stream>>>(qb, kb, a_l);
  att_pv_k<<<dim3(64, 8), 512, 0, stream>>>(qb, kb, Vt, a_l, attn, Obuf);

  // fused epilogue: Wo + fc1 + fc2
  tail_k<<<256, 256, 0, stream>>>(Obuf, htkg, Wo, bo, fc1_W, fc1_b, fc2_W, fc2_b, out);
}

// Round 5
// 578.385 us; speedup vs baseline: 1.2988x; 1.0039x over previous
//
#include <hip/hip_runtime.h>
#include <cstdint>
#include <cstddef>

#define NN 8192
#define EE 262144
#define ET 270336   // EE + NN self loops

using short8  = __attribute__((ext_vector_type(8))) short;
using floatx4 = __attribute__((ext_vector_type(4))) float;

__device__ __forceinline__ unsigned short f2bf(float f) {
  unsigned int u = __float_as_uint(f);
  u += 0x7fffu + ((u >> 16) & 1u);          // RNE
  return (unsigned short)(u >> 16);
}

// ---------------- CSR build, both graphs in one launch ----------------
__global__ void edge_hist2_k(const int* __restrict__ ei_t, const int* __restrict__ ei_e,
                             int* __restrict__ cnt_t, int* __restrict__ cnt_e) {
  int idx = blockIdx.x * 256 + threadIdx.x;
  int g = idx >= ET;                        // block-uniform (ET % 256 == 0)
  int e = g ? idx - ET : idx;
  const int* ei = g ? ei_e : ei_t;
  int* cnt = g ? cnt_e : cnt_t;
  int d = (e < EE) ? ei[EE + e] : (e - EE);
  atomicAdd(&cnt[d], 1);
}

__global__ void scan2_k(int* cnt_t, int* off_t, int* cnt_e, int* off_e) {
  int* cnt = blockIdx.x ? cnt_e : cnt_t;    // pos aliases cnt (overwritten)
  int* off = blockIdx.x ? off_e : off_t;
  __shared__ int s[1024];
  int t = threadIdx.x;
  int v[8]; int base = t * 8; int sum = 0;
  #pragma unroll
  for (int j = 0; j < 8; ++j) { v[j] = cnt[base + j]; sum += v[j]; }
  s[t] = sum; __syncthreads();
  for (int o = 1; o < 1024; o <<= 1) {
    int x = (t >= o) ? s[t - o] : 0;
    __syncthreads();
    s[t] += x;
    __syncthreads();
  }
  int excl = s[t] - sum;
  #pragma unroll
  for (int j = 0; j < 8; ++j) { off[base + j] = excl; cnt[base + j] = excl; excl += v[j]; }
  if (t == 1023) off[NN] = excl;
}

__global__ void edge_scatter2_k(const int* __restrict__ ei_t, const int* __restrict__ ei_e,
                                int* __restrict__ pos_t, int* __restrict__ pos_e,
                                int* __restrict__ srcs_t, int* __restrict__ srcs_e) {
  int idx = blockIdx.x * 256 + threadIdx.x;
  int g = idx >= ET;
  int e = g ? idx - ET : idx;
  const int* ei = g ? ei_e : ei_t;
  int* pos = g ? pos_e : pos_t;
  int* srcs = g ? srcs_e : srcs_t;
  int sv, d;
  if (e < EE) { sv = ei[e]; d = ei[EE + e]; } else { sv = d = e - EE; }
  int p = atomicAdd(&pos[d], 1);
  srcs[p] = sv;
}

// ---------------- shared GEMM inner loop ----------------
__device__ __forceinline__ void gemm_core(const float* __restrict__ A, int lda, int K,
                                          const float* __restrict__ Bs, int row0, int col,
                                          float acc[8]) {
  #pragma unroll
  for (int r = 0; r < 8; ++r) acc[r] = 0.f;
  for (int k = 0; k < K; k += 4) {
    float b0 = Bs[(k + 0) * 32 + col], b1 = Bs[(k + 1) * 32 + col];
    float b2 = Bs[(k + 2) * 32 + col], b3 = Bs[(k + 3) * 32 + col];
    #pragma unroll
    for (int r = 0; r < 8; ++r) {
      const float4 a4 = *(const float4*)(A + (size_t)(row0 + r) * lda + k);
      acc[r] = fmaf(a4.x, b0, acc[r]);
      acc[r] = fmaf(a4.y, b1, acc[r]);
      acc[r] = fmaf(a4.z, b2, acc[r]);
      acc[r] = fmaf(a4.w, b3, acc[r]);
    }
  }
}

// ---------------- mm_x: h1 = x@gat1_W (+att_sd epilogue), hg1 = x@gcn1_W ----------------
__global__ __launch_bounds__(256) void mm_x_k(const float* __restrict__ x,
    const float* __restrict__ Wgat, const float* __restrict__ Wgcn,
    const float* __restrict__ as_w, const float* __restrict__ ad_w,
    float* __restrict__ h1, float* __restrict__ hg1,
    float* __restrict__ a_s1, float* __restrict__ a_d1) {
  __shared__ float Bs[256 * 32];
  const int tid = threadIdx.x, by = blockIdx.y;
  const bool gat = by < 4;
  const int NC = gat ? 128 : 64;
  const int c0 = gat ? by * 32 : (by - 4) * 32;
  const float* B = gat ? Wgat : Wgcn;
  for (int idx = tid; idx < 256 * 32; idx += 256)
    Bs[idx] = B[(idx >> 5) * NC + c0 + (idx & 31)];
  __syncthreads();
  const int row0 = blockIdx.x * 64 + (tid >> 5) * 8;
  const int col = tid & 31;
  float acc[8];
  gemm_core(x, 256, 256, Bs, row0, col, acc);
  if (gat) {
    #pragma unroll
    for (int r = 0; r < 8; ++r) h1[(size_t)(row0 + r) * 128 + c0 + col] = acc[r];
    const int head = c0 >> 6;
    const float asw = as_w[head * 64 + (c0 & 63) + col];
    const float adw = ad_w[head * 64 + (c0 & 63) + col];
    float ps[8], pd[8];
    #pragma unroll
    for (int r = 0; r < 8; ++r) { ps[r] = acc[r] * asw; pd[r] = acc[r] * adw; }
    #pragma unroll
    for (int m = 16; m >= 1; m >>= 1)
      #pragma unroll
      for (int r = 0; r < 8; ++r) { ps[r] += __shfl_xor(ps[r], m); pd[r] += __shfl_xor(pd[r], m); }
    if (col == 0) {
      #pragma unroll
      for (int r = 0; r < 8; ++r) {
        atomicAdd(&a_s1[(row0 + r) * 2 + head], ps[r]);
        atomicAdd(&a_d1[(row0 + r) * 2 + head], pd[r]);
      }
    }
  } else {
    #pragma unroll
    for (int r = 0; r < 8; ++r) hg1[(size_t)(row0 + r) * 64 + c0 + col] = acc[r];
  }
}

// ---------------- GAT aggregation ----------------
// Inner gather loop padded to x4 (zero weights) so the compiler can keep 4
// independent L2 gathers in flight (dynamic trip count otherwise blocks unroll).
template<int H, int C>
__device__ __forceinline__ void gat_agg_body(const float* __restrict__ h,
    const float* __restrict__ a_s, const float* __restrict__ a_d,
    const int* __restrict__ off, const int* __restrict__ srcs,
    const float* __restrict__ bias, float* __restrict__ out, int ldout, int b) {
  constexpr int HC = H * C;
  const int tid = threadIdx.x;
  const int hd = tid / C;
  const int r0 = off[b], r1 = off[b + 1];
  __shared__ int s_src[HC];
  __shared__ float s_w[HC][H];
  float ad[H];
  #pragma unroll
  for (int hh = 0; hh < H; ++hh) ad[hh] = a_d[b * H + hh];
  float acc = 0.f, den = 0.f;
  for (int base = r0; base < r1; base += HC) {
    const int cnt = min(HC, r1 - base);
    const int cnt4 = (cnt + 3) & ~3;
    __syncthreads();
    int e = base + tid;
    if (e < r1) {
      int sv = srcs[e];
      s_src[tid] = sv;
      #pragma unroll
      for (int hh = 0; hh < H; ++hh) {
        float xv = a_s[sv * H + hh] + ad[hh];
        xv = xv > 0.f ? xv : 0.2f * xv;     // leaky_relu 0.2
        s_w[tid][hh] = __expf(xv);
      }
    } else if (tid < cnt4) {                // zero-weight padding
      s_src[tid] = 0;
      #pragma unroll
      for (int hh = 0; hh < H; ++hh) s_w[tid][hh] = 0.f;
    }
    __syncthreads();
    for (int j = 0; j < cnt4; j += 4) {
      #pragma unroll
      for (int u = 0; u < 4; ++u) {
        float wv = s_w[j + u][hd];
        den += wv;
        acc = fmaf(wv, h[(size_t)s_src[j + u] * HC + tid], acc);
      }
    }
  }
  float o = acc / den + bias[tid];
  out[(size_t)b * ldout + tid] = o > 0.f ? o : (__expf(o) - 1.f);  // elu
}

template<int H, int C>
__global__ void gat_agg_k(const float* __restrict__ h, const float* __restrict__ a_s,
                          const float* __restrict__ a_d, const int* __restrict__ off,
                          const int* __restrict__ srcs, const float* __restrict__ bias,
                          float* __restrict__ out, int ldout) {
  gat_agg_body<H, C>(h, a_s, a_d, off, srcs, bias, out, ldout, blockIdx.x);
}

// ---------------- merged: gat1 aggregation (blocks 0..NN) + gcn1 agg+gemv (2 nodes/blk) ----
__global__ __launch_bounds__(128) void agg1_k(
    const float* __restrict__ h1, const float* __restrict__ a_s1, const float* __restrict__ a_d1,
    const int* __restrict__ off_t, const int* __restrict__ src_t,
    const float* __restrict__ gat1_b, float* __restrict__ g1out,
    const float* __restrict__ hg1, const int* __restrict__ off_e, const int* __restrict__ src_e,
    const float* __restrict__ gcn1_b, const float* __restrict__ gcn2_W, float* __restrict__ h2g) {
  const int tid = threadIdx.x;
  if (blockIdx.x < NN) {
    gat_agg_body<2, 64>(h1, a_s1, a_d1, off_t, src_t, gat1_b, g1out, 128, blockIdx.x);
  } else {
    const int nb = (blockIdx.x - NN) * 2;
    const int sub = tid >> 6, t = tid & 63;
    const int node = nb + sub;
    __shared__ int s_src2[2][64];
    __shared__ float s_nrm2[2][64];
    __shared__ float s_row2[2][64];
    const int r0 = off_e[node], r1 = off_e[node + 1];
    const int cA = off_e[nb + 1] - off_e[nb];
    const int cB = off_e[nb + 2] - off_e[nb + 1];
    const int trips = (max(cA, cB) + 63) >> 6;
    float dinv_b = rsqrtf((float)max(r1 - r0, 1));
    float acc = 0.f;
    for (int it = 0; it < trips; ++it) {
      const int cnt = min(64, r1 - (r0 + it * 64));
      const int cnt4 = (cnt + 3) & ~3;
      __syncthreads();
      int e = r0 + it * 64 + t;
      if (e < r1) {
        int sv = src_e[e];
        s_src2[sub][t] = sv;
        int ds = off_e[sv + 1] - off_e[sv];
        s_nrm2[sub][t] = dinv_b * rsqrtf((float)max(ds, 1));
      } else if (t < cnt4) {
        s_src2[sub][t] = 0;
        s_nrm2[sub][t] = 0.f;
      }
      __syncthreads();
      for (int j = 0; j < cnt4; j += 4) {
        #pragma unroll
        for (int u = 0; u < 4; ++u)
          acc = fmaf(s_nrm2[sub][j + u], hg1[(size_t)s_src2[sub][j + u] * 64 + t], acc);
      }
    }
    s_row2[sub][t] = fmaxf(acc + gcn1_b[t], 0.f);
    __syncthreads();
    float acc2 = 0.f;
    for (int k = 0; k < 64; ++k)
      acc2 = fmaf(s_row2[sub][k], gcn2_W[k * 64 + t], acc2);
    h2g[(size_t)node * 64 + t] = acc2;
  }
}

// ---------------- merged: mm_gat2 (blocks 0..256) + gcn_agg2 (4 nodes/blk) ----------------
__global__ __launch_bounds__(256) void mm2_k(
    const float* __restrict__ g1out, const float* __restrict__ gat2_W,
    const float* __restrict__ gat2_as, const float* __restrict__ gat2_ad,
    float* __restrict__ h2, float* __restrict__ a_s2, float* __restrict__ a_d2,
    const float* __restrict__ h2g, const int* __restrict__ off_e, const int* __restrict__ src_e,
    const float* __restrict__ gcn2_b, float* __restrict__ hekg) {
  const int tid = threadIdx.x;
  if (blockIdx.x < 256) {
    __shared__ float Bs[128 * 32];
    const int bx = blockIdx.x & 127;
    const int c0 = (blockIdx.x >> 7) * 32;
    for (int idx = tid; idx < 128 * 32; idx += 256)
      Bs[idx] = gat2_W[(idx >> 5) * 64 + c0 + (idx & 31)];
    __syncthreads();
    const int row0 = bx * 64 + (tid >> 5) * 8;
    const int col = tid & 31;
    float acc[8];
    gemm_core(g1out, 128, 128, Bs, row0, col, acc);
    const float asw = gat2_as[c0 + col];
    const float adw = gat2_ad[c0 + col];
    float ps[8], pd[8];
    #pragma unroll
    for (int r = 0; r < 8; ++r) {
      h2[(size_t)(row0 + r) * 64 + c0 + col] = acc[r];
      ps[r] = acc[r] * asw; pd[r] = acc[r] * adw;
    }
    #pragma unroll
    for (int m = 16; m >= 1; m >>= 1)
      #pragma unroll
      for (int r = 0; r < 8; ++r) { ps[r] += __shfl_xor(ps[r], m); pd[r] += __shfl_xor(pd[r], m); }
    if (col == 0) {
      #pragma unroll
      for (int r = 0; r < 8; ++r) {
        atomicAdd(&a_s2[row0 + r], ps[r]);
        atomicAdd(&a_d2[row0 + r], pd[r]);
      }
    }
  } else {
    const int nb = (blockIdx.x - 256) * 4;
    const int sub = tid >> 6, t = tid & 63;
    const int node = nb + sub;
    __shared__ int s_src4[4][64];
    __shared__ float s_nrm4[4][64];
    const int r0 = off_e[node], r1 = off_e[node + 1];
    int cmax = 0;
    #pragma unroll
    for (int i = 0; i < 4; ++i) cmax = max(cmax, off_e[nb + i + 1] - off_e[nb + i]);
    const int trips = (cmax + 63) >> 6;
    float dinv_b = rsqrtf((float)max(r1 - r0, 1));
    float acc = 0.f;
    for (int it = 0; it < trips; ++it) {
      const int cnt = min(64, r1 - (r0 + it * 64));
      const int cnt4 = (cnt + 3) & ~3;
      __syncthreads();
      int e = r0 + it * 64 + t;
      if (e < r1) {
        int sv = src_e[e];
        s_src4[sub][t] = sv;
        int ds = off_e[sv + 1] - off_e[sv];
        s_nrm4[sub][t] = dinv_b * rsqrtf((float)max(ds, 1));
      } else if (t < cnt4) {
        s_src4[sub][t] = 0;
        s_nrm4[sub][t] = 0.f;
      }
      __syncthreads();
      for (int j = 0; j < cnt4; j += 4) {
        #pragma unroll
        for (int u = 0; u < 4; ++u)
          acc = fmaf(s_nrm4[sub][j + u], h2g[(size_t)s_src4[sub][j + u] * 64 + t], acc);
      }
    }
    hekg[(size_t)node * 64 + t] = fmaxf(acc + gcn2_b[t], 0.f);
  }
}

// ---------------- qkv projections (+V transpose) ----------------
__global__ __launch_bounds__(256) void mm_qkv_k(const float* __restrict__ htkg,
    const float* __restrict__ hekg,
    const float* __restrict__ Wq, const float* __restrict__ bq,
    const float* __restrict__ Wk, const float* __restrict__ bk,
    const float* __restrict__ Wv, const float* __restrict__ bv,
    unsigned short* __restrict__ qb, unsigned short* __restrict__ kb,
    unsigned short* __restrict__ Vt) {
  __shared__ float Bs[64 * 32];
  __shared__ float Ts[32][65];
  const int tid = threadIdx.x, by = blockIdx.y;
  const int kind = by >> 1;
  const int c0 = (by & 1) * 32;
  const float* A = (kind == 0) ? htkg : hekg;
  const float* B = (kind == 0) ? Wq : (kind == 1) ? Wk : Wv;
  const float* bias = (kind == 0) ? bq : (kind == 1) ? bk : bv;
  for (int idx = tid; idx < 64 * 32; idx += 256)
    Bs[idx] = B[(idx >> 5) * 64 + c0 + (idx & 31)];
  __syncthreads();
  const int row0 = blockIdx.x * 64 + (tid >> 5) * 8;
  const int col = tid & 31;
  float acc[8];
  gemm_core(A, 64, 64, Bs, row0, col, acc);
  const float bb = bias[c0 + col];
  if (kind == 0) {
    const float SCL = 0.17677669529663687f * 1.4426950408889634f;  // 1/sqrt(32) * log2(e)
    #pragma unroll
    for (int r = 0; r < 8; ++r)
      qb[(size_t)(row0 + r) * 64 + c0 + col] = f2bf((acc[r] + bb) * SCL);
  } else if (kind == 1) {
    #pragma unroll
    for (int r = 0; r < 8; ++r)
      kb[(size_t)(row0 + r) * 64 + c0 + col] = f2bf(acc[r] + bb);
  } else {
    const int rl = (tid >> 5) * 8;
    #pragma unroll
    for (int r = 0; r < 8; ++r) Ts[col][rl + r] = acc[r] + bb;
    __syncthreads();
    const int c = tid >> 3, rr = (tid & 7) * 8;
    short8 pk;
    #pragma unroll
    for (int j = 0; j < 8; ++j) pk[j] = (short)f2bf(Ts[c][rr + j]);
    *(short8*)(Vt + (size_t)(c0 + c) * NN + blockIdx.x * 64 + rr) = pk;
  }
}

// ---------------- attention pass 1: softmax denominators ----------------
// grid (64,8), 512 thr (8 waves; 16 q-rows each). Block = 128 q-rows x 1024-key split.
// K tiles (64 keys, 8KB) staged to LDS (XOR-swizzled, reg-staged, double-buffered),
// shared by all waves. 512 blocks -> 2 blocks/CU x 8 waves = 16 waves/CU.
__global__ __launch_bounds__(512) void att_lsum_k(
    const unsigned short* __restrict__ qb, const unsigned short* __restrict__ kb,
    float* __restrict__ lsum) {
  __shared__ __align__(16) short Kbuf[2][64 * 64];
  const int tid = threadIdx.x;
  const int lane = tid & 63, wv = tid >> 6;
  const int ql = lane & 15, quad = lane >> 4;
  const int q0 = blockIdx.x * 128 + wv * 16;
  const int k0 = blockIdx.y * 1024;
  const floatx4 zf = {0.f, 0.f, 0.f, 0.f};

  short8 qf[2];
  #pragma unroll
  for (int h = 0; h < 2; ++h)
    qf[h] = *(const short8*)(qb + (size_t)(q0 + ql) * 64 + h * 32 + quad * 8);

  const int sr = tid >> 3, sc = tid & 7;     // staging: row sr (0..63), colblk sc
  const int swc = (sc ^ (sr & 7)) * 8;
  short8 krg;

  float lacc[2][4];
  #pragma unroll
  for (int h = 0; h < 2; ++h)
    #pragma unroll
    for (int r = 0; r < 4; ++r) lacc[h][r] = 0.f;

  // prologue: stage tile 0
  {
    krg = *(const short8*)(kb + (size_t)(k0 + sr) * 64 + sc * 8);
    *(short8*)&Kbuf[0][sr * 64 + swc] = krg;
  }
  __syncthreads();

  for (int t = 0; t < 16; ++t) {
    if (t < 15)
      krg = *(const short8*)(kb + (size_t)(k0 + (t + 1) * 64 + sr) * 64 + sc * 8);
    const short* Kc = Kbuf[t & 1];
    #pragma unroll
    for (int kt = 0; kt < 4; ++kt) {
      const int row = kt * 16 + ql;
      short8 kf[2];
      #pragma unroll
      for (int h = 0; h < 2; ++h)
        kf[h] = *(const short8*)&Kc[row * 64 + ((h * 4 + quad) ^ (row & 7)) * 8];
      #pragma unroll
      for (int h = 0; h < 2; ++h) {
        floatx4 s = __builtin_amdgcn_mfma_f32_16x16x32_bf16(qf[h], kf[h], zf, 0, 0, 0);
        #pragma unroll
        for (int r = 0; r < 4; ++r) lacc[h][r] += __builtin_amdgcn_exp2f(s[r]);
      }
    }
    if (t < 15)
      *(short8*)&Kbuf[(t + 1) & 1][sr * 64 + swc] = krg;
    __syncthreads();
  }

  #pragma unroll
  for (int o = 8; o >= 1; o >>= 1)
    #pragma unroll
    for (int h = 0; h < 2; ++h)
      #pragma unroll
      for (int r = 0; r < 4; ++r)
        lacc[h][r] += __shfl_xor(lacc[h][r], o, 16);
  if (ql == 0) {
    #pragma unroll
    for (int h = 0; h < 2; ++h)
      #pragma unroll
      for (int r = 0; r < 4; ++r)
        atomicAdd(&lsum[(q0 + quad * 4 + r) * 2 + h], lacc[h][r]);
  }
}

// ---------------- attention pass 2: P/attn/PV with LDS-shared K/V tiles ----------------
// grid (64,8), 512 thr (8 waves). Block = 128 q-rows x 1024-key split; wave = 16 q-rows.
// K and V 64-key tiles staged once per block (double-buffered, XOR-swizzled).
// attn head-mean written straight from registers; O partials via global f32 atomics.
__global__ __launch_bounds__(512, 4) void att_pv_k(
    const unsigned short* __restrict__ qb, const unsigned short* __restrict__ kb,
    const unsigned short* __restrict__ Vt, const float* __restrict__ lsum,
    float* __restrict__ attn, float* __restrict__ O) {
  __shared__ __align__(16) short Kbuf[2][64 * 64];
  __shared__ __align__(16) short Vbuf[2][64 * 64];
  __shared__ __align__(16) float Esh[8][2][16 * 36];
  const int tid = threadIdx.x;
  const int lane = tid & 63, wv = tid >> 6;
  const int ql = lane & 15, quad = lane >> 4;
  const int q0 = blockIdx.x * 128 + wv * 16;
  const int k0 = blockIdx.y * 1024;
  const floatx4 zf = {0.f, 0.f, 0.f, 0.f};

  short8 qf[2];
  #pragma unroll
  for (int h = 0; h < 2; ++h)
    qf[h] = *(const short8*)(qb + (size_t)(q0 + ql) * 64 + h * 32 + quad * 8);

  float invl[2][4];
  #pragma unroll
  for (int h = 0; h < 2; ++h)
    #pragma unroll
    for (int r = 0; r < 4; ++r)
      invl[h][r] = 1.0f / lsum[(q0 + quad * 4 + r) * 2 + h];

  const int sr = tid >> 3, sc = tid & 7;   // staging row (0..63), colblk (0..7)
  const int swc = (sc ^ (sr & 7)) * 8;
  short8 krg, vrg;

  floatx4 oacc[2][2];
  #pragma unroll
  for (int h = 0; h < 2; ++h)
    #pragma unroll
    for (int hf = 0; hf < 2; ++hf) oacc[h][hf] = zf;

  // prologue: stage tile 0
  {
    krg = *(const short8*)(kb + (size_t)(k0 + sr) * 64 + sc * 8);
    vrg = *(const short8*)(Vt + (size_t)sr * NN + k0 + sc * 8);
    *(short8*)&Kbuf[0][sr * 64 + swc] = krg;
    *(short8*)&Vbuf[0][sr * 64 + swc] = vrg;
  }
  __syncthreads();

  for (int t = 0; t < 16; ++t) {
    if (t < 15) {
      krg = *(const short8*)(kb + (size_t)(k0 + (t + 1) * 64 + sr) * 64 + sc * 8);
      vrg = *(const short8*)(Vt + (size_t)sr * NN + k0 + (t + 1) * 64 + sc * 8);
    }
    const short* Kc = Kbuf[t & 1];
    const short* Vc = Vbuf[t & 1];
    #pragma unroll
    for (int ks = 0; ks < 2; ++ks) {
      short8 kf[2][2], vf[2][2];
      #pragma unroll
      for (int kt = 0; kt < 2; ++kt) {
        const int row = ks * 32 + kt * 16 + ql;
        #pragma unroll
        for (int h = 0; h < 2; ++h)
          kf[kt][h] = *(const short8*)&Kc[row * 64 + ((h * 4 + quad) ^ (row & 7)) * 8];
      }
      #pragma unroll
      for (int h = 0; h < 2; ++h)
        #pragma unroll
        for (int hf = 0; hf < 2; ++hf) {
          const int d = h * 32 + hf * 16 + ql;
          vf[h][hf] = *(const short8*)&Vc[d * 64 + ((ks * 4 + quad) ^ (d & 7)) * 8];
        }

      floatx4 p[2][2];  // [head][kt]
      #pragma unroll
      for (int h = 0; h < 2; ++h)
        #pragma unroll
        for (int kt = 0; kt < 2; ++kt) {
          floatx4 s = __builtin_amdgcn_mfma_f32_16x16x32_bf16(qf[h], kf[kt][h], zf, 0, 0, 0);
          #pragma unroll
          for (int r = 0; r < 4; ++r)
            p[h][kt][r] = __builtin_amdgcn_exp2f(s[r]) * invl[h][r];
        }
      // attn head-mean straight from registers (line completes within sub-step)
      #pragma unroll
      for (int kt = 0; kt < 2; ++kt)
        #pragma unroll
        for (int r = 0; r < 4; ++r)
          attn[(size_t)(q0 + quad * 4 + r) * NN + k0 + t * 64 + ks * 32 + kt * 16 + ql] =
              0.5f * (p[0][kt][r] + p[1][kt][r]);
      // C-layout -> LDS -> A-layout, PV mfma
      #pragma unroll
      for (int h = 0; h < 2; ++h)
        #pragma unroll
        for (int kt = 0; kt < 2; ++kt)
          #pragma unroll
          for (int r = 0; r < 4; ++r)
            Esh[wv][h][(quad * 4 + r) * 36 + kt * 16 + ql] = p[h][kt][r];
      #pragma unroll
      for (int h = 0; h < 2; ++h) {
        const float* ep = &Esh[wv][h][ql * 36 + quad * 8];
        float4 x0 = *(const float4*)ep;
        float4 x1 = *(const float4*)(ep + 4);
        short8 ef;
        ef[0] = (short)f2bf(x0.x); ef[1] = (short)f2bf(x0.y);
        ef[2] = (short)f2bf(x0.z); ef[3] = (short)f2bf(x0.w);
        ef[4] = (short)f2bf(x1.x); ef[5] = (short)f2bf(x1.y);
        ef[6] = (short)f2bf(x1.z); ef[7] = (short)f2bf(x1.w);
        #pragma unroll
        for (int hf = 0; hf < 2; ++hf)
          oacc[h][hf] = __builtin_amdgcn_mfma_f32_16x16x32_bf16(ef, vf[h][hf], oacc[h][hf], 0, 0, 0);
      }
    }
    if (t < 15) {
      *(short8*)&Kbuf[(t + 1) & 1][sr * 64 + swc] = krg;
      *(short8*)&Vbuf[(t + 1) & 1][sr * 64 + swc] = vrg;
    }
    __syncthreads();
  }

  #pragma unroll
  for (int h = 0; h < 2; ++h)
    #pragma unroll
    for (int hf = 0; hf < 2; ++hf)
      #pragma unroll
      for (int r = 0; r < 4; ++r)
        atomicAdd(&O[(size_t)(q0 + quad * 4 + r) * 64 + h * 32 + hf * 16 + ql], oacc[h][hf][r]);
}

// ---------------- tail: h_attn=O@Wo+bo ; y1=relu([htkg|h_attn]@fc1+b) ; pred=y1@fc2+b ----
__global__ __launch_bounds__(256) void tail_k(const float* __restrict__ O,
    const float* __restrict__ htkg, const float* __restrict__ Wo, const float* __restrict__ bo,
    const float* __restrict__ fc1W, const float* __restrict__ fc1b,
    const float* __restrict__ fc2W, const float* __restrict__ fc2b,
    float* __restrict__ pred) {
  __shared__ float Ws[8192];
  __shared__ float T1[2048];
  __shared__ float T2[2048];
  const int tid = threadIdx.x;
  const int col = tid & 63, rg = tid >> 6;
  const int rowbase = blockIdx.x * 32;
  for (int i = tid; i < 2048; i += 256) T1[i] = O[(size_t)rowbase * 64 + i];
  for (int i = tid; i < 4096; i += 256) Ws[i] = Wo[i];
  const float rbo = bo[col], rf1b = fc1b[col], rf2 = fc2W[col], rf2b = fc2b[0];
  __syncthreads();
  float ha[8];
  #pragma unroll
  for (int r = 0; r < 8; ++r) {
    const int row = rg * 8 + r;
    float acc = rbo;
    for (int k = 0; k < 64; ++k) acc = fmaf(T1[row * 64 + k], Ws[k * 64 + col], acc);
    ha[r] = acc;
  }
  __syncthreads();
  #pragma unroll
  for (int r = 0; r < 8; ++r) T2[(rg * 8 + r) * 64 + col] = ha[r];
  for (int i = tid; i < 2048; i += 256) T1[i] = htkg[(size_t)rowbase * 64 + i];
  for (int i = tid; i < 8192; i += 256) Ws[i] = fc1W[i];
  __syncthreads();
  #pragma unroll
  for (int r = 0; r < 8; ++r) {
    const int row = rg * 8 + r;
    float acc = rf1b;
    for (int k = 0; k < 64; ++k) acc = fmaf(T1[row * 64 + k], Ws[k * 64 + col], acc);
    for (int k = 0; k < 64; ++k) acc = fmaf(T2[row * 64 + k], Ws[(64 + k) * 64 + col], acc);
    float y = fmaxf(acc, 0.f);
    float v = y * rf2;
    #pragma unroll
    for (int m = 32; m >= 1; m >>= 1) v += __shfl_xor(v, m);
    if (col == 0) pred[rowbase + row] = v + rf2b;
  }
}

extern "C" void kernel_launch(void* const* d_in, const int* in_sizes, int n_in,
                              void* d_out, int out_size, void* d_ws, size_t ws_size,
                              hipStream_t stream) {
  (void)in_sizes; (void)n_in; (void)out_size; (void)ws_size;
  const float* x       = (const float*)d_in[0];
  const int*   ei_t    = (const int*)d_in[1];
  const int*   ei_e    = (const int*)d_in[2];
  const float* gat1_W  = (const float*)d_in[3];
  const float* gat1_as = (const float*)d_in[4];
  const float* gat1_ad = (const float*)d_in[5];
  const float* gat1_b  = (const float*)d_in[6];
  const float* gat2_W  = (const float*)d_in[7];
  const float* gat2_as = (const float*)d_in[8];
  const float* gat2_ad = (const float*)d_in[9];
  const float* gat2_b  = (const float*)d_in[10];
  const float* gcn1_W  = (const float*)d_in[11];
  const float* gcn1_b  = (const float*)d_in[12];
  const float* gcn2_W  = (const float*)d_in[13];
  const float* gcn2_b  = (const float*)d_in[14];
  const float* Wq = (const float*)d_in[15]; const float* bq = (const float*)d_in[16];
  const float* Wk = (const float*)d_in[17]; const float* bk = (const float*)d_in[18];
  const float* Wv = (const float*)d_in[19]; const float* bv = (const float*)d_in[20];
  const float* Wo = (const float*)d_in[21]; const float* bo = (const float*)d_in[22];
  const float* fc1_W = (const float*)d_in[23]; const float* fc1_b = (const float*)d_in[24];
  const float* fc2_W = (const float*)d_in[25]; const float* fc2_b = (const float*)d_in[26];

  float* out  = (float*)d_out;
  float* attn = out + NN;   // [N, N] fp32, after pred[N]

  char* wsp = (char*)d_ws;
  size_t ofs = 0;
  auto take = [&](size_t bytes) -> char* {
    char* p = wsp + ofs;
    ofs = (ofs + bytes + 255) & ~(size_t)255;
    return p;
  };
  // ---- contiguous zero-init region first (single memset) ----
  int*   pos_t = (int*)take(NN * 4);
  int*   pos_e = (int*)take(NN * 4);
  float* a_s1  = (float*)take((size_t)NN * 2 * 4);
  float* a_d1  = (float*)take((size_t)NN * 2 * 4);
  float* a_s2  = (float*)take((size_t)NN * 4);
  float* a_d2  = (float*)take((size_t)NN * 4);
  float* a_l   = (float*)take((size_t)NN * 2 * 4);
  float* Obuf  = (float*)take((size_t)NN * 64 * 4);
  const size_t zero_span = ofs;
  // ---- rest ----
  int* off_t = (int*)take((NN + 1) * 4);
  int* off_e = (int*)take((NN + 1) * 4);
  int* src_t = (int*)take((size_t)ET * 4);
  int* src_e = (int*)take((size_t)ET * 4);
  float* h1    = (float*)take((size_t)NN * 128 * 4);
  float* g1out = (float*)take((size_t)NN * 128 * 4);
  float* h2    = (float*)take((size_t)NN * 64 * 4);
  float* htkg  = (float*)take((size_t)NN * 64 * 4);
  float* hg1   = (float*)take((size_t)NN * 64 * 4);
  float* h2g   = (float*)take((size_t)NN * 64 * 4);
  float* hekg  = (float*)take((size_t)NN * 64 * 4);
  unsigned short* qb = (unsigned short*)take((size_t)NN * 64 * 2);
  unsigned short* kb = (unsigned short*)take((size_t)NN * 64 * 2);
  unsigned short* Vt = (unsigned short*)take((size_t)64 * NN * 2);

  hipMemsetAsync(wsp, 0, zero_span, stream);

  // CSR for both graphs
  edge_hist2_k<<<2 * ET / 256, 256, 0, stream>>>(ei_t, ei_e, pos_t, pos_e);
  scan2_k<<<2, 1024, 0, stream>>>(pos_t, off_t, pos_e, off_e);
  edge_scatter2_k<<<2 * ET / 256, 256, 0, stream>>>(ei_t, ei_e, pos_t, pos_e, src_t, src_e);

  // x projections for both branches + gat1 att_sd epilogue
  mm_x_k<<<dim3(128, 6), 256, 0, stream>>>(x, gat1_W, gcn1_W, gat1_as, gat1_ad,
                                           h1, hg1, a_s1, a_d1);
  // merged gat1-agg + gcn1-agg+gemv
  agg1_k<<<NN + NN / 2, 128, 0, stream>>>(h1, a_s1, a_d1, off_t, src_t, gat1_b, g1out,
                                          hg1, off_e, src_e, gcn1_b, gcn2_W, h2g);
  // merged mm_gat2 + gcn_agg2
  mm2_k<<<256 + NN / 4, 256, 0, stream>>>(g1out, gat2_W, gat2_as, gat2_ad, h2, a_s2, a_d2,
                                          h2g, off_e, src_e, gcn2_b, hekg);
  // gat layer-2 aggregation
  gat_agg_k<1, 64><<<NN, 64, 0, stream>>>(h2, a_s2, a_d2, off_t, src_t, gat2_b, htkg, 64);

  // qkv projections + V transpose
  mm_qkv_k<<<dim3(128, 6), 256, 0, stream>>>(htkg, hekg, Wq, bq, Wk, bk, Wv, bv, qb, kb, Vt);

  // attention: q-block 128 x k-split 8, LDS-shared K/V tiles
  att_lsum_k<<<dim3(64, 8), 512, 0, stream>>>(qb, kb, a_l);
  att_pv_k<<<dim3(64, 8), 512, 0, stream>>>(qb, kb, Vt, a_l, attn, Obuf);

  // fused epilogue: Wo + fc1 + fc2
  tail_k<<<256, 256, 0, stream>>>(Obuf, htkg, Wo, bo, fc1_W, fc1_b, fc2_W, fc2_b, out);
}